// Round 15
// baseline (734.245 us; speedup 1.0000x reference)
//
#include <hip/hip_runtime.h>
#include <hip/hip_bf16.h>
#include <cstdint>
#include <cstddef>

typedef unsigned short u16;
typedef unsigned int u32;
typedef __attribute__((ext_vector_type(8))) __bf16 bfx8;
typedef __attribute__((ext_vector_type(4))) float f32x4;

static __device__ __forceinline__ float bitf(u32 v){ float f; __builtin_memcpy(&f,&v,4); return f; }
static __device__ __forceinline__ float bf2f(u16 v){ return bitf(((u32)v)<<16); }
static __device__ __forceinline__ u16 f2bf(float f){ __bf16 b=(__bf16)f; u16 r; __builtin_memcpy(&r,&b,2); return r; }
static __device__ __forceinline__ u32 pk2(float a,float b){ return (u32)f2bf(a) | ((u32)f2bf(b)<<16); }
static __device__ __forceinline__ void unpk8(uint4 r, float* o){
  o[0]=bitf(r.x<<16); o[1]=bitf(r.x&0xffff0000u);
  o[2]=bitf(r.y<<16); o[3]=bitf(r.y&0xffff0000u);
  o[4]=bitf(r.z<<16); o[5]=bitf(r.z&0xffff0000u);
  o[6]=bitf(r.w<<16); o[7]=bitf(r.w&0xffff0000u);
}
static __device__ __forceinline__ void unpk4(uint2 r, float* o){
  o[0]=bitf(r.x<<16); o[1]=bitf(r.x&0xffff0000u);
  o[2]=bitf(r.y<<16); o[3]=bitf(r.y&0xffff0000u);
}
static __device__ __forceinline__ void async16(void* lds, const void* g){
  __builtin_amdgcn_global_load_lds((const __attribute__((address_space(1))) u32*)g,
                                   (__attribute__((address_space(3))) u32*)lds, 16, 0, 0);
}

// ---------------- GEMM: C[M][N] = A[M][K] @ B[N][K]^T (+ epilogue) -----------
// EPI: 0=+bias, 2=BN+ReLU, 3=+bias+add, 4=raw fp32, 5=*rowsc+bias+add,
//      6=raw bf16, 7=+bias column-routed (n0<512 -> C/ldc, else C2/ldc2 at col-512)
// AMODE 2: conv3 dy-grouped split-K (z = dy+1, K=1536, dx from k0>>9)
struct GemmArgs {
  const u16* A; long aZ; int lda;
  const u16* Bw; long bZ; int ldb;
  const float* bias; int biasZ;
  const float* scale; const float* shift;
  const u16* add; long addZ;
  const float* rowsc; long rowscZ;
  u16* C; long cZ; int ldc; int colOff;
  u16* C2; long c2Z; int ldc2;
  int K;
  const u16* pad;
  int dirBase;
};

template<int AMODE, int EPI>
__global__ __launch_bounds__(256)
void gemm_bt(GemmArgs g)
{
  __shared__ u16 smA[128*64];
  __shared__ u16 smB[128*64];
  const int tid = threadIdx.x;
  const int l = tid & 63;
  const int wv = tid >> 6;
  const int wr = wv >> 1, wc = wv & 1;
  const int z = blockIdx.z;
  const int r0 = blockIdx.x * 128;
  const int n0 = blockIdx.y * 128;

  const u16* Abase = g.A + (size_t)z * g.aZ;
  const u16* Bbase = g.Bw + (size_t)z * g.bZ;
  const int ldb = g.ldb ? g.ldb : g.K;

  f32x4 acc[4][4];
  #pragma unroll
  for (int i=0;i<4;i++)
    #pragma unroll
    for (int j=0;j<4;j++) acc[i][j] = (f32x4){0.f,0.f,0.f,0.f};

  const int nkt = g.K >> 6;
  #pragma unroll 1
  for (int kt=0; kt<nkt; ++kt) {
    const int k0 = kt << 6;
    #pragma unroll
    for (int it=0; it<4; ++it) {
      const int s = it*256 + tid;
      const int row = s >> 3, ch = s & 7;
      const u16* ga;
      if (AMODE == 0) {
        ga = Abase + (size_t)(r0+row) * g.lda + k0 + ch*8;
      } else if (AMODE == 1) {
        int rr = r0 + row; int li = rr & 4095; int bb = rr >> 12;
        int dir = g.dirBase + z;
        int l2 = (dir & 2) ? (4095 - li) : li;
        int sl = (dir & 1) ? (((l2 & 63) << 6) | (l2 >> 6)) : l2;
        ga = Abase + (size_t)((bb << 12) | sl) * g.lda + k0 + ch*8;
      } else if (AMODE == 2) {
        int rr = r0 + row; int bb = rr >> 12; int li = rr & 4095;
        int yy = li >> 6, xx = li & 63;
        int dy = z - 1, dx = (k0 >> 9) - 1, kin = k0 & 511;
        ga = g.pad + (((size_t)(bb*66 + yy+dy+1))*66 + (xx+dx+1))*512 + kin + ch*8;
      } else {
        int rr = r0 + row; int bb = rr >> 12; int li = rr & 4095;
        int yy = li >> 6, xx = li & 63;
        ga = g.pad + (((size_t)(bb*66 + yy+1))*66 + (xx+1))*512 + k0 + ch*8;
      }
      async16(&smA[(size_t)(it*256 + (tid & ~63))*8], ga);
      const u16* gb = Bbase + (size_t)(n0+row) * ldb + k0 + ch*8;
      async16(&smB[(size_t)(it*256 + (tid & ~63))*8], gb);
    }
    __syncthreads();
    #pragma unroll
    for (int kk=0; kk<2; ++kk) {
      bfx8 av[4], bv[4];
      #pragma unroll
      for (int mi=0; mi<4; ++mi) {
        int ra = wr*64 + mi*16 + (l & 15);
        av[mi] = *(const bfx8*)&smA[ra*64 + kk*32 + (l>>4)*8];
      }
      #pragma unroll
      for (int ni=0; ni<4; ++ni) {
        int rb = wc*64 + ni*16 + (l & 15);
        bv[ni] = *(const bfx8*)&smB[rb*64 + kk*32 + (l>>4)*8];
      }
      #pragma unroll
      for (int mi=0; mi<4; ++mi)
        #pragma unroll
        for (int ni=0; ni<4; ++ni)
          acc[mi][ni] = __builtin_amdgcn_mfma_f32_16x16x32_bf16(av[mi], bv[ni], acc[mi][ni], 0, 0, 0);
    }
    __syncthreads();
  }

  const float* bias_d = (EPI == 0 || EPI == 3 || EPI == 5 || EPI == 7) ? g.bias + (size_t)z * g.biasZ : nullptr;
  const u16* add_d = (EPI == 3 || EPI == 5) ? g.add + (size_t)z * g.addZ : nullptr;
  const float* rowsc_d = (EPI == 5) ? g.rowsc + (size_t)z * g.rowscZ : nullptr;
  u16* Cd = g.C + (size_t)z * g.cZ;
  u16* Cd2 = (EPI == 7) ? g.C2 + (size_t)z * g.c2Z : nullptr;
  float* Cf = (float*)g.C + (size_t)z * g.cZ;
  #pragma unroll
  for (int mi=0; mi<4; ++mi) {
    #pragma unroll
    for (int ni=0; ni<4; ++ni) {
      f32x4 v = acc[mi][ni];
      const int gr = r0 + wr*64 + mi*16 + ((l >> 4) << 2);
      const int gc = n0 + wc*64 + ni*16 + (l & 15);
      #pragma unroll
      for (int q=0; q<4; ++q) {
        const int r = gr + q;
        float x = v[q];
        if (EPI == 2) {
          x = fmaxf(fmaf(x, g.scale[gc], g.shift[gc]), 0.f);
          Cd[(size_t)r * g.ldc + g.colOff + gc] = f2bf(x);
        } else if (EPI == 3) {
          x += bias_d[gc] + bf2f(add_d[(size_t)r * g.ldc + gc]);
          Cd[(size_t)r * g.ldc + g.colOff + gc] = f2bf(x);
        } else if (EPI == 5) {
          x = x * rowsc_d[r] + bias_d[gc] + bf2f(add_d[(size_t)r * g.ldc + gc]);
          Cd[(size_t)r * g.ldc + g.colOff + gc] = f2bf(x);
        } else if (EPI == 4) {
          Cf[(size_t)r * g.ldc + g.colOff + gc] = x;
        } else if (EPI == 6) {
          Cd[(size_t)r * g.ldc + g.colOff + gc] = f2bf(x);
        } else if (EPI == 7) {
          x += bias_d[gc];
          if (n0 < 512) Cd[(size_t)r * g.ldc + gc] = f2bf(x);
          else          Cd2[(size_t)r * g.ldc2 + (gc - 512)] = f2bf(x);
        } else {
          x += bias_d[gc];
          Cd[(size_t)r * g.ldc + g.colOff + gc] = f2bf(x);
        }
      }
    }
  }
}

// ---------------- small utility kernels --------------------------------------
__global__ void castk(const float* __restrict__ s, u16* __restrict__ d, int n)
{
  int i = (blockIdx.x*256 + threadIdx.x)*4;
  if (i < n){
    float4 v = *(const float4*)(s+i);
    ushort4 o; o.x=f2bf(v.x); o.y=f2bf(v.y); o.z=f2bf(v.z); o.w=f2bf(v.w);
    *(ushort4*)(d+i) = o;
  }
}

// cast m_out W with norm gain folded in
__global__ void castg(const float* __restrict__ s, const float* __restrict__ gw,
                      u16* __restrict__ d)
{
  int i = (blockIdx.x*256 + threadIdx.x)*4;
  int dd = i >> 17, k = i & 511;
  float4 v = *(const float4*)(s+i);
  float4 g4 = *(const float4*)(gw + dd*512 + k);
  ushort4 o; o.x=f2bf(v.x*g4.x); o.y=f2bf(v.y*g4.y); o.z=f2bf(v.z*g4.z); o.w=f2bf(v.w*g4.w);
  *(ushort4*)(d+i) = o;
}

__global__ void c3rep(const float* __restrict__ w, u16* __restrict__ o)
{
  int id = blockIdx.x*256 + threadIdx.x;
  int oc = id / 4608, rem = id % 4608;
  int tap = rem >> 9, ic = rem & 511;
  o[id] = f2bf(w[((size_t)oc*512 + ic)*9 + tap]);
}

__global__ void bnssk(const float* g3,const float* b3,const float* m3,const float* v3,
                      const float* g1,const float* b1,const float* m1,const float* v1,
                      float* out)
{
  int t = threadIdx.x; int i = t & 127;
  if (t < 128){ float sc = g3[i]*rsqrtf(v3[i]+1e-5f); out[i]=sc; out[128+i]=b3[i]-m3[i]*sc; }
  else        { float sc = g1[i]*rsqrtf(v1[i]+1e-5f); out[256+i]=sc; out[384+i]=b1[i]-m1[i]*sc; }
}

// reduce 3 bf16 partials -> BN+ReLU -> bf16 into zin cols 0..127
__global__ __launch_bounds__(256)
void c3red(const u16* __restrict__ P, const float* __restrict__ bnss, u16* __restrict__ zin)
{
  const int id = blockIdx.x*256 + threadIdx.x;
  const size_t base = (size_t)id * 8;
  const int r = (int)(base >> 7), c = (int)(base & 127);
  float s[8] = {0,0,0,0,0,0,0,0};
  #pragma unroll
  for (int z=0; z<3; ++z){
    uint4 raw = *(const uint4*)(P + (size_t)z*2097152 + base);
    float v[8]; unpk8(raw, v);
    #pragma unroll
    for (int j=0;j<8;j++) s[j] += v[j];
  }
  uint4 o;
  float r8[8];
  #pragma unroll
  for (int j=0;j<8;j++)
    r8[j] = fmaxf(fmaf(s[j], bnss[c+j], bnss[128+c+j]), 0.f);
  o.x = pk2(r8[0],r8[1]); o.y = pk2(r8[2],r8[3]);
  o.z = pk2(r8[4],r8[5]); o.w = pk2(r8[6],r8[7]);
  *(uint4*)(zin + (size_t)r*256 + c) = o;
}

__global__ __launch_bounds__(256)
void padk(const float* __restrict__ curr, const float* __restrict__ prev, u16* __restrict__ pad)
{
  const int id = blockIdx.x*256 + threadIdx.x;
  const int c8 = id & 63;
  int t = id >> 6;
  const int xx = t % 66; t /= 66;
  const int yy = t % 66; const int b = t / 66;
  const int c0 = c8*8;
  uint4 o;
  if (yy==0 || yy==65 || xx==0 || xx==65){ o.x=0;o.y=0;o.z=0;o.w=0; }
  else {
    const int l = (yy-1)*64 + (xx-1);
    const float* s = (c0 < 256) ? curr + ((size_t)b*4096 + l)*256 + c0
                                : prev + ((size_t)b*4096 + l)*256 + (c0-256);
    float4 a = *(const float4*)s, bb = *(const float4*)(s+4);
    o.x = pk2(a.x,a.y); o.y = pk2(a.z,a.w); o.z = pk2(bb.x,bb.y); o.w = pk2(bb.z,bb.w);
  }
  *(uint4*)(pad + (((size_t)b*66 + yy)*66 + xx)*512 + c0) = o;
}

__global__ __launch_bounds__(256)
void ln256(const u16* __restrict__ in, long inZ, u16* __restrict__ out, long outZ,
           const float* __restrict__ gw, const float* __restrict__ bw, int pz)
{
  const int z = blockIdx.z;
  const int row = blockIdx.x*4 + (threadIdx.x>>6);
  const int l = threadIdx.x & 63;
  const u16* ip = in + (size_t)z*inZ + (size_t)row*256 + l*4;
  ushort4 rr = *(const ushort4*)ip;
  float v0=bf2f(rr.x), v1=bf2f(rr.y), v2=bf2f(rr.z), v3=bf2f(rr.w);
  float s = v0+v1+v2+v3;
  float ss = v0*v0+v1*v1+v2*v2+v3*v3;
  #pragma unroll
  for(int m=1;m<64;m<<=1){ s += __shfl_xor(s,m); ss += __shfl_xor(ss,m); }
  float mu = s*(1.f/256.f);
  float var = ss*(1.f/256.f) - mu*mu;
  float rs = rsqrtf(var + 1e-5f);
  const float* g = gw + (size_t)z*pz; const float* b = bw + (size_t)z*pz;
  int c = l*4;
  u16* op = out + (size_t)z*outZ + (size_t)row*256 + c;
  ushort4 o; o.x=f2bf((v0-mu)*rs*g[c]+b[c]); o.y=f2bf((v1-mu)*rs*g[c+1]+b[c+1]);
  o.z=f2bf((v2-mu)*rs*g[c+2]+b[c+2]); o.w=f2bf((v3-mu)*rs*g[c+3]+b[c+3]);
  *(ushort4*)op = o;
}

// sum 8 head partial SS -> inverse RMS per row
__global__ __launch_bounds__(256)
void rsumk(const float* __restrict__ RS8, float* __restrict__ RS)
{
  const int z = blockIdx.z;
  const int row = blockIdx.x*256 + threadIdx.x;
  const float* p = RS8 + ((size_t)z*16384 + row)*8;
  float4 a = *(const float4*)p, b = *(const float4*)(p+4);
  float s = a.x+a.y+a.z+a.w+b.x+b.y+b.z+b.w;
  RS[(size_t)z*16384 + row] = rsqrtf(s*(1.f/512.f) + 1e-5f);
}

// fp32 dt head: dt = softplus(xln.W_dt + b + dt_bias)
__global__ __launch_bounds__(256)
void dtk(const u16* __restrict__ xln, const float* __restrict__ minW,
         const float* __restrict__ minB, const float* __restrict__ dtb,
         float* __restrict__ DT)
{
  __shared__ float sx[32*257];
  const int z = blockIdx.z;
  const int r0 = blockIdx.x * 32;
  const int tid = threadIdx.x;
  {
    const int rr = tid >> 3, cc = (tid & 7) * 32;
    const u16* src = xln + ((size_t)z*16384 + r0 + rr)*256 + cc;
    #pragma unroll
    for (int q=0;q<4;q++){
      uint4 raw = *(const uint4*)(src + q*8);
      float v[8]; unpk8(raw, v);
      #pragma unroll
      for (int j=0;j<8;j++) sx[rr*257 + cc + q*8 + j] = v[j];
    }
  }
  __syncthreads();
  const int ri = tid >> 3, hv = tid & 7;
  const float* wrow = minW + ((size_t)z*1288 + 1280 + hv)*256;
  float acc = 0.f;
  #pragma unroll 4
  for (int k=0; k<256; k+=4){
    float4 wq = *(const float4*)(wrow + k);
    acc += sx[ri*257+k]*wq.x + sx[ri*257+k+1]*wq.y + sx[ri*257+k+2]*wq.z + sx[ri*257+k+3]*wq.w;
  }
  acc += minB[(size_t)z*1288 + 1280 + hv] + dtb[z*8 + hv];
  float dt = (acc > 20.f) ? acc : log1pf(expf(acc));
  DT[((size_t)z*16384 + r0 + ri)*8 + hv] = dt;
}

// chunk-local cumulative log-decay
__global__ __launch_bounds__(256)
void cak(const float* __restrict__ DT, float* __restrict__ CA,
         const float* __restrict__ alog, int dirBase)
{
  const int z = blockIdx.z;
  const int gidx = blockIdx.x*4 + (threadIdx.x>>6);
  const int lane = threadIdx.x & 63;
  const int c = gidx & 63, bh = gidx >> 6;
  const int b = bh >> 3, hh = bh & 7;
  const size_t row = (size_t)z*16384 + (size_t)b*4096 + c*64 + lane;
  float x = DT[row*8 + hh];
  #pragma unroll
  for (int m=1;m<64;m<<=1){ float o = __shfl_up(x, m); if (lane >= m) x += o; }
  float eA = expf(alog[(dirBase+z)*8 + hh]);
  CA[row*8 + hh] = -eA * x;
}

// fused: conv1d(4)+SiLU on B/C columns + C-half -> BCC + B-transpose -> BT
//        + head-shared raw scores S -> SR.   grid (256,1,nd) per (b,c)
__global__ __launch_bounds__(256)
void bck(const u16* __restrict__ xbcr, u16* __restrict__ bcc, u16* __restrict__ bt,
         u16* __restrict__ SR, const float* __restrict__ cw, const float* __restrict__ cb)
{
  __shared__ u16 BCs[64*264];   // [s][B:0..127, C:128..255]
  __shared__ u16 Tb[128*72];    // [n][s] transposed B
  __shared__ float cwS[4][256];
  __shared__ float cbS[256];
  const int bx = blockIdx.x, z = blockIdx.z;
  const int c = bx & 63, b = bx >> 6;
  const int tid = threadIdx.x, l = tid & 63, w = tid >> 6;
  const u16* xb = xbcr + (size_t)z*16777216 + (size_t)b*4096*768;
  const float* cwp = cw + (size_t)z*3072;
  const float* cbp = cb + (size_t)z*768;
  {
    float4 w4 = *(const float4*)(cwp + (512 + tid)*4);
    cwS[0][tid]=w4.x; cwS[1][tid]=w4.y; cwS[2][tid]=w4.z; cwS[3][tid]=w4.w;
    cbS[tid] = cbp[512 + tid];
  }
  __syncthreads();
  #pragma unroll
  for (int u=0; u<8; ++u){
    int idx = u*256 + tid;
    int s = idx >> 5, c8 = idx & 31;
    int li = c*64 + s;
    int col = 512 + c8*8;
    float acc[8];
    #pragma unroll
    for (int j=0;j<8;j++) acc[j] = cbS[c8*8+j];
    #pragma unroll
    for (int tap=0; tap<4; ++tap){
      int lt = li - 3 + tap;
      if (lt >= 0){
        uint4 raw = *(const uint4*)(xb + (size_t)lt*768 + col);
        float v[8]; unpk8(raw, v);
        #pragma unroll
        for (int j=0;j<8;j++) acc[j] = fmaf(v[j], cwS[tap][c8*8+j], acc[j]);
      }
    }
    u16 o8[8];
    #pragma unroll
    for (int j=0;j<8;j++) o8[j] = f2bf(acc[j] / (1.f + __expf(-acc[j])));
    *(uint4*)&BCs[s*264 + c8*8] = *(const uint4*)o8;
    if (c8 >= 16){
      *(uint4*)(bcc + ((size_t)z*16384 + (size_t)b*4096 + li)*256 + c8*8) = *(const uint4*)o8;
    } else {
      #pragma unroll
      for (int j=0;j<8;j++) Tb[(c8*8+j)*72 + s] = o8[j];
    }
  }
  __syncthreads();
  // S = C@B^T (16 MFMA)
  bfx8 av[4];
  #pragma unroll
  for (int kk=0; kk<4; ++kk)
    av[kk] = *(const bfx8*)&BCs[(w*16 + (l&15))*264 + 128 + kk*32 + (l>>4)*8];
  f32x4 sacc[4];
  #pragma unroll
  for (int i=0;i<4;i++) sacc[i] = (f32x4){0.f,0.f,0.f,0.f};
  #pragma unroll
  for (int kk=0; kk<4; ++kk)
    #pragma unroll
    for (int st=0; st<4; ++st){
      bfx8 bv = *(const bfx8*)&BCs[(st*16 + (l&15))*264 + kk*32 + (l>>4)*8];
      sacc[st] = __builtin_amdgcn_mfma_f32_16x16x32_bf16(av[kk], bv, sacc[st], 0, 0, 0);
    }
  // SR stride per (z,b) is 262144 u16 (64 chunks x 4096)
  u16* Sd = SR + ((size_t)z*4 + b)*262144 + (size_t)c*4096;
  const int t0 = w*16 + ((l>>4)<<2);
  #pragma unroll
  for (int st=0; st<4; ++st){
    int s = st*16 + (l&15);
    u32* cp = (u32*)&Sd[(size_t)s*64 + t0];
    cp[0] = pk2(sacc[st][0], sacc[st][1]);
    cp[1] = pk2(sacc[st][2], sacc[st][3]);
  }
  #pragma unroll
  for (int u=0; u<4; ++u){
    int idx = u*256 + tid;
    int n = idx >> 3, sg = idx & 7;
    uint4 v = *(const uint4*)&Tb[n*72 + sg*8];
    *(uint4*)(bt + (size_t)z*2097152 + (size_t)n*16384 + (size_t)b*4096 + c*64 + sg*8) = v;
  }
}

// conv1d(4)+SiLU on X cols (raw 0..511) + transpose -> XCT[p][g]
__global__ __launch_bounds__(256)
void convx(const u16* __restrict__ xbcr, u16* __restrict__ xct,
           const float* __restrict__ cw, const float* __restrict__ cb)
{
  __shared__ u16 T[128*72];
  __shared__ float cwX[4][128];
  __shared__ float cbX[128];
  const int bx = blockIdx.x, z = blockIdx.z;
  const int pq = bx & 3, c = (bx>>2) & 63, b = bx >> 8;
  const int tid = threadIdx.x;
  const u16* xb = xbcr + (size_t)z*16777216 + (size_t)b*4096*768;
  if (tid < 128){
    float4 w4 = *(const float4*)(cw + (size_t)z*3072 + (pq*128+tid)*4);
    cwX[0][tid]=w4.x; cwX[1][tid]=w4.y; cwX[2][tid]=w4.z; cwX[3][tid]=w4.w;
    cbX[tid] = cb[z*768 + pq*128 + tid];
  }
  __syncthreads();
  #pragma unroll
  for (int u=0; u<4; ++u){
    int idx = u*256 + tid;
    int s = idx >> 4, seg = idx & 15;
    int li = c*64 + s;
    int col = pq*128 + seg*8;
    float acc[8];
    #pragma unroll
    for (int j=0;j<8;j++) acc[j] = cbX[seg*8+j];
    #pragma unroll
    for (int tap=0; tap<4; ++tap){
      int lt = li - 3 + tap;
      if (lt >= 0){
        uint4 raw = *(const uint4*)(xb + (size_t)lt*768 + col);
        float v[8]; unpk8(raw, v);
        #pragma unroll
        for (int j=0;j<8;j++) acc[j] = fmaf(v[j], cwX[tap][seg*8+j], acc[j]);
      }
    }
    #pragma unroll
    for (int j=0;j<8;j++)
      T[(seg*8+j)*72 + s] = f2bf(acc[j] / (1.f + __expf(-acc[j])));
  }
  __syncthreads();
  #pragma unroll
  for (int u=0; u<4; ++u){
    int idx = u*256 + tid;
    int pl = idx >> 3, sg = idx & 7;
    uint4 v = *(const uint4*)&T[pl*72 + sg*8];
    *(uint4*)(xct + (size_t)z*8388608 + (size_t)(pq*128+pl)*16384 + b*4096 + c*64 + sg*8) = v;
  }
}

// per-chunk outer products, heads fused, p-quarter per block; grid (1024,1,nd)
__global__ __launch_bounds__(256)
void csk(const u16* __restrict__ xct, const u16* __restrict__ bt,
         const float* __restrict__ DT, const float* __restrict__ CA,
         u16* __restrict__ CS)
{
  __shared__ u16 Xw[128*72];
  __shared__ u16 Bt[128*72];
  __shared__ float wS[64*2];
  const int bx = blockIdx.x, z = blockIdx.z;
  const int pq = bx & 3, c = (bx>>2) & 63, b = bx >> 8;
  const int tid = threadIdx.x, l = tid & 63, w = tid >> 6;
  const size_t rowb = (size_t)z*16384 + (size_t)b*4096;
  const int p0 = pq*128;
  if (tid < 128){
    int s = tid & 63, hi = tid >> 6;
    int hh = pq*2 + hi;
    float ca63 = CA[(rowb + c*64 + 63)*8 + hh];
    float cav  = CA[(rowb + c*64 + s)*8 + hh];
    float dtv  = DT[(rowb + c*64 + s)*8 + hh];
    wS[s*2+hi] = __expf(ca63 - cav) * dtv;
  }
  __syncthreads();
  #pragma unroll
  for (int u=0; u<4; ++u){
    int idx = u*256 + tid;
    int pl = idx >> 3, sg = idx & 7;
    int hi = pl >> 6;
    uint4 raw = *(const uint4*)(xct + (size_t)z*8388608 + (size_t)(p0+pl)*16384 + b*4096 + c*64 + sg*8);
    float v[8]; unpk8(raw, v);
    uint4 o;
    o.x = pk2(v[0]*wS[(sg*8+0)*2+hi], v[1]*wS[(sg*8+1)*2+hi]);
    o.y = pk2(v[2]*wS[(sg*8+2)*2+hi], v[3]*wS[(sg*8+3)*2+hi]);
    o.z = pk2(v[4]*wS[(sg*8+4)*2+hi], v[5]*wS[(sg*8+5)*2+hi]);
    o.w = pk2(v[6]*wS[(sg*8+6)*2+hi], v[7]*wS[(sg*8+7)*2+hi]);
    *(uint4*)&Xw[pl*72 + sg*8] = o;
  }
  #pragma unroll
  for (int u=0; u<4; ++u){
    int idx = u*256 + tid;
    int n = idx >> 3, sg = idx & 7;
    *(uint4*)&Bt[n*72 + sg*8] =
      *(const uint4*)(bt + (size_t)z*2097152 + (size_t)n*16384 + b*4096 + c*64 + sg*8);
  }
  __syncthreads();
  f32x4 acc[8][2];
  #pragma unroll
  for (int i=0;i<8;i++)
    #pragma unroll
    for (int j=0;j<2;j++) acc[i][j] = (f32x4){0.f,0.f,0.f,0.f};
  #pragma unroll
  for (int kk=0; kk<2; ++kk){
    bfx8 bvp[2];
    #pragma unroll
    for (int ni=0; ni<2; ++ni)
      bvp[ni] = *(const bfx8*)&Xw[(w*32 + ni*16 + (l&15))*72 + kk*32 + (l>>4)*8];
    #pragma unroll
    for (int mi=0; mi<8; ++mi){
      bfx8 av = *(const bfx8*)&Bt[(mi*16 + (l&15))*72 + kk*32 + (l>>4)*8];
      #pragma unroll
      for (int ni=0; ni<2; ++ni)
        acc[mi][ni] = __builtin_amdgcn_mfma_f32_16x16x32_bf16(av, bvp[ni], acc[mi][ni], 0, 0, 0);
    }
  }
  #pragma unroll
  for (int mi=0; mi<8; ++mi){
    #pragma unroll
    for (int ni=0; ni<2; ++ni){
      int gp = p0 + w*32 + ni*16 + (l&15);
      int bhx = b*8 + (gp>>6); int pin = gp & 63;
      int n0 = mi*16 + ((l>>4)<<2);
      u32* cp = (u32*)&CS[(size_t)z*16777216 + (size_t)bhx*524288 + (size_t)c*8192 + (size_t)pin*128 + n0];
      cp[0] = pk2(acc[mi][ni][0], acc[mi][ni][1]);
      cp[1] = pk2(acc[mi][ni][2], acc[mi][ni][3]);
    }
  }
}

// sequential 64-step combine IN PLACE (H aliases CS); 2x n-split
__global__ __launch_bounds__(256)
void combk(const u16* __restrict__ CS, const float* __restrict__ CA,
           u16* __restrict__ H)
{
  __shared__ float aL[64];
  const int bx = blockIdx.x;
  const int z = blockIdx.z;
  const int nh = bx & 1, pg = (bx >> 1) & 3, bh = bx >> 3;
  const int b = bh >> 3, hh = bh & 7;
  const int tid = threadIdx.x;
  const int p = pg*16 + (tid >> 4), n = nh*64 + (tid & 15)*4;
  const size_t rowb = (size_t)z*16384 + (size_t)b*4096;
  if (tid < 64) aL[tid] = __expf(CA[(rowb + tid*64 + 63)*8 + hh]);
  __syncthreads();
  const u16* Cs = CS + (size_t)z*16777216 + (size_t)bh*524288 + (size_t)p*128 + n;
  u16* Hd = H + (size_t)z*16777216 + (size_t)bh*524288 + (size_t)p*128 + n;
  float h[4];
  #pragma unroll
  for (int j=0;j<4;j++) h[j]=0.f;
  uint2 pf = *(const uint2*)Cs;
  #pragma unroll 1
  for (int c=0; c<64; ++c){
    uint2 cur = pf;
    if (c < 63) pf = *(const uint2*)(Cs + (size_t)(c+1)*8192);
    uint2 o;
    o.x = pk2(h[0],h[1]); o.y = pk2(h[2],h[3]);
    *(uint2*)(Hd + (size_t)c*8192) = o;
    float v[4]; unpk4(cur, v);
    const float a = aL[c];
    #pragma unroll
    for (int j=0;j<4;j++) h[j] = fmaf(h[j], a, v[j]);
  }
}

// per-chunk output: Y = (S_decayed @ X + diag(exp(ca)) * (C @ H[c]) + Dh*x) * silu(z)
// scores loaded direct to regs; LDS 36.4KB -> 4 blocks/CU
__global__ __launch_bounds__(256)
void yk2(const u16* __restrict__ bcc, const u16* __restrict__ xct,
         const u16* __restrict__ SR,
         const float* __restrict__ DT, const float* __restrict__ CA,
         const u16* __restrict__ H, const float* __restrict__ Dp,
         u16* __restrict__ Y, float* __restrict__ RS8)
{
  __shared__ u16 Hs[64*136];
  __shared__ u16 Xt[64*72];
  __shared__ u16 Sm[64*72];     // decayed scores; reused as Z/Y tile late
  __shared__ float caL[64], dtL[64];
  const int bx = blockIdx.x, z = blockIdx.z;
  const int c = bx & 63, bh = bx >> 6;
  const int b = bh >> 3, hh = bh & 7;
  const int tid = threadIdx.x, l = tid & 63, w = tid >> 6;
  const size_t rowb = (size_t)z*16384 + (size_t)b*4096;
  const u16* bcp = bcc + (rowb + c*64)*256;
  const u16* Hd = H + (size_t)z*16777216 + (size_t)bh*524288 + (size_t)c*8192;
  const u16* xcp = xct + (size_t)z*8388608 + (size_t)(hh*64)*16384 + b*4096 + c*64;
  const u16* Sd = SR + ((size_t)z*4 + b)*262144 + (size_t)c*4096;
  const float Dh = Dp[z*8 + hh];
  const int t0 = w*16 + ((l>>4)<<2);

  uint2 sv[4];
  #pragma unroll
  for (int st=0; st<4; ++st)
    sv[st] = *(const uint2*)(Sd + (size_t)(st*16 + (l&15))*64 + t0);
  bfx8 av[4];
  #pragma unroll
  for (int kk=0; kk<4; ++kk)
    av[kk] = *(const bfx8*)(bcp + (size_t)(w*16 + (l&15))*256 + 128 + kk*32 + (l>>4)*8);

  if (tid < 64){
    caL[tid] = CA[(rowb + c*64 + tid)*8 + hh];
    dtL[tid] = DT[(rowb + c*64 + tid)*8 + hh];
  }
  #pragma unroll
  for (int u=0; u<4; ++u){
    int idx = u*256 + tid; int p = idx >> 4, sg = idx & 15;
    *(uint4*)&Hs[p*136 + sg*8] = *(const uint4*)(Hd + (size_t)p*128 + sg*8);
  }
  #pragma unroll
  for (int u=0; u<2; ++u){
    int idx = u*256 + tid; int p = idx >> 3, sg = idx & 7;
    *(uint4*)&Xt[p*72 + sg*8] = *(const uint4*)(xcp + (size_t)p*16384 + sg*8);
  }
  __syncthreads();

  f32x4 acc2[4];
  #pragma unroll
  for (int i=0;i<4;i++) acc2[i] = (f32x4){0.f,0.f,0.f,0.f};
  #pragma unroll
  for (int kk=0; kk<4; ++kk)
    #pragma unroll
    for (int st=0; st<4; ++st){
      bfx8 hv = *(const bfx8*)&Hs[(st*16 + (l&15))*136 + kk*32 + (l>>4)*8];
      acc2[st] = __builtin_amdgcn_mfma_f32_16x16x32_bf16(av[kk], hv, acc2[st], 0, 0, 0);
    }
  #pragma unroll
  for (int st=0; st<4; ++st){
    int s = st*16 + (l&15);
    #pragma unroll
    for (int q=0;q<4;q++){
      int t = t0 + q;
      u32 wv2 = (q < 2) ? sv[st].x : sv[st].y;
      u16 sraw = (q & 1) ? (u16)(wv2 >> 16) : (u16)(wv2 & 0xffff);
      float m = (s <= t) ? __expf(caL[t]-caL[s]) * dtL[s] : 0.f;
      Sm[t*72 + s] = f2bf(bf2f(sraw) * m);
    }
  }
  #pragma unroll
  for (int pt=0; pt<4; ++pt)
    #pragma unroll
    for (int q=0;q<4;q++){
      int t = t0 + q;
      acc2[pt][q] *= __expf(caL[t]);
    }
  __syncthreads();          // Sm ready
  #pragma unroll
  for (int kk=0; kk<2; ++kk){
    bfx8 svx = *(const bfx8*)&Sm[(w*16 + (l&15))*72 + kk*32 + (l>>4)*8];
    #pragma unroll
    for (int pt=0; pt<4; ++pt){
      bfx8 bv = *(const bfx8*)&Xt[(pt*16 + (l&15))*72 + kk*32 + (l>>4)*8];
      acc2[pt] = __builtin_amdgcn_mfma_f32_16x16x32_bf16(svx, bv, acc2[pt], 0, 0, 0);
    }
  }
  __syncthreads();          // Sm reads done; reuse as Zs
  u16* Zs = Sm;
  u16* Yrow = Y + (rowb + c*64)*512 + hh*64;
  #pragma unroll
  for (int u=0; u<2; ++u){
    int idx = u*256 + tid; int t = idx >> 3, sg = idx & 7;
    *(uint4*)&Zs[t*72 + sg*8] = *(const uint4*)(Yrow + (size_t)t*512 + sg*8);
  }
  __syncthreads();          // Zs ready
  float ssq[4] = {0.f,0.f,0.f,0.f};
  #pragma unroll
  for (int pt=0; pt<4; ++pt){
    #pragma unroll
    for (int q=0;q<4;q++){
      int t = t0 + q;
      int p = pt*16 + (l&15);
      float xv = bf2f(Xt[p*72 + t]);
      float zf = bf2f(Zs[t*72 + p]);
      float yv = (acc2[pt][q] + Dh*xv) * (zf/(1.f+__expf(-zf)));
      ssq[q] += yv*yv;
      Zs[t*72 + p] = f2bf(yv);
    }
  }
  #pragma unroll
  for (int q=0;q<4;q++){
    float s = ssq[q];
    s += __shfl_xor(s, 1); s += __shfl_xor(s, 2);
    s += __shfl_xor(s, 4); s += __shfl_xor(s, 8);
    if ((l & 15) == 0){
      int t = t0 + q;
      RS8[(rowb + c*64 + t)*8 + hh] = s;
    }
  }
  __syncthreads();
  #pragma unroll
  for (int u=0; u<2; ++u){
    int idx = u*256 + tid; int t = idx >> 3, sg = idx & 7;
    *(uint4*)(Yrow + (size_t)t*512 + sg*8) = *(const uint4*)&Zs[t*72 + sg*8];
  }
}

__global__ __launch_bounds__(256)
void finalk(const float* __restrict__ curr, const u16* __restrict__ outs, float* __restrict__ o)
{
  const int row = blockIdx.x*4 + (threadIdx.x>>6);
  const int c4 = (threadIdx.x & 63)*4;
  const int b = row >> 12, li = row & 4095;
  const int T = ((li & 63) << 6) | (li >> 6);
  const size_t rb = (size_t)b*4096;
  const ushort4 a0 = *(const ushort4*)(outs + (size_t)0*4194304 + ((rb+li)*256 + c4));
  const ushort4 a1 = *(const ushort4*)(outs + (size_t)1*4194304 + ((rb+T)*256 + c4));
  const ushort4 a2 = *(const ushort4*)(outs + (size_t)2*4194304 + ((rb+4095-li)*256 + c4));
  const ushort4 a3 = *(const ushort4*)(outs + (size_t)3*4194304 + ((rb+4095-T)*256 + c4));
  float4 cv = *(const float4*)(curr + (size_t)row*256 + c4);
  float4 r;
  r.x = cv.x + 0.25f*(bf2f(a0.x)+bf2f(a1.x)+bf2f(a2.x)+bf2f(a3.x));
  r.y = cv.y + 0.25f*(bf2f(a0.y)+bf2f(a1.y)+bf2f(a2.y)+bf2f(a3.y));
  r.z = cv.z + 0.25f*(bf2f(a0.z)+bf2f(a1.z)+bf2f(a2.z)+bf2f(a3.z));
  r.w = cv.w + 0.25f*(bf2f(a0.w)+bf2f(a1.w)+bf2f(a2.w)+bf2f(a3.w));
  *(float4*)(o + (size_t)row*256 + c4) = r;
}

// ---------------------------------------------------------------------------
extern "C" void kernel_launch(void* const* d_in, const int* in_sizes, int n_in,
                              void* d_out, int out_size, void* d_ws, size_t ws_size,
                              hipStream_t stream)
{
  (void)in_sizes; (void)n_in; (void)out_size;
  const float* curr   = (const float*)d_in[0];
  const float* prev   = (const float*)d_in[1];
  const float* conv3w = (const float*)d_in[2];
  const float* bn3g=(const float*)d_in[3], *bn3b=(const float*)d_in[4], *bn3m=(const float*)d_in[5], *bn3v=(const float*)d_in[6];
  const float* conv1w = (const float*)d_in[7];
  const float* bn1g=(const float*)d_in[8], *bn1b=(const float*)d_in[9], *bn1m=(const float*)d_in[10], *bn1v=(const float*)d_in[11];
  const float* fuseW=(const float*)d_in[12], *fuseB=(const float*)d_in[13];
  const float* lng=(const float*)d_in[14], *lnb=(const float*)d_in[15];
  const float* inpW=(const float*)d_in[16], *inpB=(const float*)d_in[17];
  const float* mlng=(const float*)d_in[18], *mlnb=(const float*)d_in[19];
  const float* minW=(const float*)d_in[20], *minB=(const float*)d_in[21];
  const float* cw=(const float*)d_in[22], *cb=(const float*)d_in[23];
  const float* alog=(const float*)d_in[24], *Dp=(const float*)d_in[25], *dtb=(const float*)d_in[26];
  const float* mng=(const float*)d_in[27];
  const float* moutW=(const float*)d_in[28], *moutB=(const float*)d_in[29];
  const float* outpW=(const float*)d_in[30], *outpB=(const float*)d_in[31];

  // ---- persistent layout ----
  char* ws = (char*)d_ws;
  size_t off = 0;
  auto alloc = [&](size_t bytes){ size_t o = off; off = (off + bytes + 1023) & ~(size_t)1023; return o; };
  const size_t O_WFUSE = alloc((size_t)256*256*2);
  const size_t O_WINP  = alloc((size_t)4*256*256*2);
  const size_t O_WMIN  = alloc((size_t)4*1288*256*2);
  const size_t O_WMOUT = alloc((size_t)4*256*512*2);
  const size_t O_WOUTP = alloc((size_t)4*256*256*2);
  const size_t O_WC3   = alloc((size_t)128*4608*2);
  const size_t O_WC1   = alloc((size_t)128*512*2);
  const size_t O_BNSS  = alloc(512*4);
  const size_t O_ZF    = alloc((size_t)16384*256*2);
  const size_t O_OUTS  = alloc((size_t)4*16384*256*2);
  const size_t O_P     = off;

  // per-dir sizes (bytes)
  const size_t S0d  = (size_t)16384*256*2;
  const size_t XLNd = (size_t)16384*256*2;
  const size_t Yd   = (size_t)16384*512*2;
  const size_t XCTd = (size_t)512*16384*2;
  const size_t BTd  = (size_t)128*16384*2;
  const size_t DTd  = (size_t)16384*8*4;
  const size_t CAd  = (size_t)16384*8*4;
  const size_t SRd  = (size_t)4*64*4096*2;
  const size_t RSd  = (size_t)16384*4;
  const size_t RS8d = (size_t)16384*8*4;
  const size_t XHd  = (size_t)16777216*2;
  const size_t perdir = S0d + XLNd + Yd + XCTd + BTd + DTd + CAd + SRd + RSd + RS8d + XHd;

  const size_t PADsz = (size_t)4*66*66*512*2;
  const size_t CPsz  = (size_t)3*16384*128*2;
  const size_t PREsz = PADsz + CPsz + (size_t)16384*256*2*2 + 4096;

  int nd = 0;
  for (int cand = 4; cand >= 1; cand >>= 1) {
    size_t need = (size_t)cand*perdir; if (need < PREsz) need = PREsz;
    if (O_P + need <= ws_size) { nd = cand; break; }
  }
  if (nd == 0) return;

  #define WP(o) ((u16*)(ws + (o)))
  #define FP(o) ((float*)(ws + (o)))

  const size_t O_PAD = O_P;
  const size_t O_CP  = O_PAD + PADsz;
  const size_t O_ZIN = O_CP + CPsz;
  const size_t O_ZFT = O_ZIN + (size_t)16384*256*2;

  // 1. BN scale/shift + weight conversions
  bnssk<<<1, 256, 0, stream>>>(bn3g,bn3b,bn3m,bn3v, bn1g,bn1b,bn1m,bn1v, FP(O_BNSS));
  castk<<<64, 256, 0, stream>>>(fuseW, WP(O_WFUSE), 65536);
  castk<<<256, 256, 0, stream>>>(inpW, WP(O_WINP), 262144);
  castk<<<1288, 256, 0, stream>>>(minW, WP(O_WMIN), 1318912);
  castg<<<512, 256, 0, stream>>>(moutW, mng, WP(O_WMOUT));
  castk<<<256, 256, 0, stream>>>(outpW, WP(O_WOUTP), 262144);
  castk<<<64, 256, 0, stream>>>(conv1w, WP(O_WC1), 65536);
  c3rep<<<2304, 256, 0, stream>>>(conv3w, WP(O_WC3));
  // 2. padded concat input (bf16)
  padk<<<4356, 256, 0, stream>>>(curr, prev, WP(O_PAD));

  GemmArgs a;
  // 3. conv3 dy-grouped split-K (3 passes, K=1536) -> bf16 partials -> reduce+BN+ReLU
  a = {}; a.A = WP(O_PAD); a.pad = WP(O_PAD);
  a.Bw = WP(O_WC3); a.bZ = 1536; a.ldb = 4608;
  a.C = WP(O_CP); a.cZ = 2097152; a.ldc = 128; a.colOff = 0; a.K = 1536;
  gemm_bt<2,6><<<dim3(128,1,3), 256, 0, stream>>>(a);
  c3red<<<1024, 256, 0, stream>>>(WP(O_CP), FP(O_BNSS), WP(O_ZIN));
  // 4. conv1 -> zin[:,128:256]
  a = {}; a.A = WP(O_PAD); a.pad = WP(O_PAD); a.Bw = WP(O_WC1); a.bZ = 0; a.ldb = 512;
  a.scale = FP(O_BNSS)+256; a.shift = FP(O_BNSS)+384;
  a.C = WP(O_ZIN); a.cZ = 0; a.ldc = 256; a.colOff = 128; a.K = 512;
  gemm_bt<3,2><<<dim3(128,1,1), 256, 0, stream>>>(a);
  // 5. fuse GEMM -> zft
  a = {}; a.A = WP(O_ZIN); a.aZ = 0; a.lda = 256; a.Bw = WP(O_WFUSE); a.bZ = 0; a.ldb = 256;
  a.bias = fuseB; a.biasZ = 0; a.C = WP(O_ZFT); a.cZ = 0; a.ldc = 256; a.colOff = 0; a.K = 256;
  gemm_bt<0,0><<<dim3(128,2,1), 256, 0, stream>>>(a);
  // 6. LN -> zf (persistent)
  ln256<<<dim3(4096,1,1), 256, 0, stream>>>(WP(O_ZFT), 0, WP(O_ZF), 0, lng, lnb, 0);

  // ---- phases over directions ----
  for (int d0 = 0; d0 < 4; d0 += nd) {
    size_t o = O_P;
    const size_t O_S0  = o; o += (size_t)nd*S0d;
    const size_t O_XLN = o; o += (size_t)nd*XLNd;
    const size_t O_Y   = o; o += (size_t)nd*Yd;
    const size_t O_XCT = o; o += (size_t)nd*XCTd;
    const size_t O_BT  = o; o += (size_t)nd*BTd;
    const size_t O_DT  = o; o += (size_t)nd*DTd;
    const size_t O_CA  = o; o += (size_t)nd*CAd;
    const size_t O_SR  = o; o += (size_t)nd*SRd;
    const size_t O_RS  = o; o += (size_t)nd*RSd;
    const size_t O_RS8 = o; o += (size_t)nd*RS8d;
    const size_t O_XH  = o;
    const size_t O_BCC = O_XLN;
    const size_t O_S1  = O_XLN;

    // 7. inp GEMM (permuted rows per dir) -> s0
    a = {}; a.A = WP(O_ZF); a.aZ = 0; a.lda = 256;
    a.Bw = WP(O_WINP) + (size_t)d0*65536; a.bZ = 65536; a.ldb = 256;
    a.bias = inpB + d0*256; a.biasZ = 256;
    a.C = WP(O_S0); a.cZ = 4194304; a.ldc = 256; a.colOff = 0; a.K = 256; a.dirBase = d0;
    gemm_bt<1,0><<<dim3(128,2,nd), 256, 0, stream>>>(a);
    // 8. per-dir LN(s0) -> xln
    ln256<<<dim3(4096,1,nd), 256, 0, stream>>>(WP(O_S0), 4194304, WP(O_XLN), 4194304,
                                               mlng + d0*256, mlnb + d0*256, 256);
    // 9. dt, chunk log-decay
    dtk<<<dim3(512,1,nd), 256, 0, stream>>>(WP(O_XLN), minW + (size_t)d0*329728,
                                            minB + d0*1288, dtb + d0*8, FP(O_DT));
    cak<<<dim3(512,1,nd), 256, 0, stream>>>(FP(O_DT), FP(O_CA), alog, d0);
    // 10. fused z-gate + xBC GEMM (N=1280, column-routed epilogue)
    //     cols 0..511 -> Y (ldc 512), cols 512..1279 -> raw xbc XH (ldc 768)
    a = {}; a.A = WP(O_XLN); a.aZ = 4194304; a.lda = 256;
    a.Bw = WP(O_WMIN) + (size_t)d0*329728; a.bZ = 329728; a.ldb = 256;
    a.bias = minB + d0*1288; a.biasZ = 1288;
    a.C = WP(O_Y); a.cZ = 8388608; a.ldc = 512; a.colOff = 0;
    a.C2 = WP(O_XH); a.c2Z = 16777216; a.ldc2 = 768;
    a.K = 256;
    gemm_bt<0,7><<<dim3(128,10,nd), 256, 0, stream>>>(a);
    // 12. conv1d+SiLU+transpose X -> XCT
    convx<<<dim3(1024,1,nd), 256, 0, stream>>>(WP(O_XH), WP(O_XCT), cw + d0*3072, cb + d0*768);
    // 13. fused conv B/C + BCC(C-half) + BT + head-shared scores SR
    bck<<<dim3(256,1,nd), 256, 0, stream>>>(WP(O_XH), WP(O_BCC), WP(O_BT), WP(O_SR),
                                            cw + d0*3072, cb + d0*768);
    // 14. per-chunk outer products -> CS (overlays raw xbc; after 12&13)
    csk<<<dim3(1024,1,nd), 256, 0, stream>>>(WP(O_XCT), WP(O_BT), FP(O_DT), FP(O_CA), WP(O_XH));
    // 15. 64-step combine in place -> H
    combk<<<dim3(256,1,nd), 256, 0, stream>>>(WP(O_XH), FP(O_CA), WP(O_XH));
    // 16. per-chunk outputs -> Y in place, + per-(row,head) SS
    yk2<<<dim3(2048,1,nd), 256, 0, stream>>>(WP(O_BCC), WP(O_XCT), WP(O_SR),
                                             FP(O_DT), FP(O_CA), WP(O_XH), Dp + d0*8,
                                             WP(O_Y), FP(O_RS8));
    // 17. inverse RMS per row
    rsumk<<<dim3(64,1,nd), 256, 0, stream>>>(FP(O_RS8), FP(O_RS));
    // 18. m_out GEMM (norm fused) + s0 residual -> s1
    a = {}; a.A = WP(O_Y); a.aZ = 8388608; a.lda = 512;
    a.Bw = WP(O_WMOUT) + (size_t)d0*131072; a.bZ = 131072; a.ldb = 512;
    a.bias = moutB + d0*256; a.biasZ = 256;
    a.add = WP(O_S0); a.addZ = 4194304;
    a.rowsc = FP(O_RS); a.rowscZ = 16384;
    a.C = WP(O_S1); a.cZ = 4194304; a.ldc = 256; a.colOff = 0; a.K = 512;
    gemm_bt<0,5><<<dim3(128,2,nd), 256, 0, stream>>>(a);
    // 19. outp GEMM -> outs (persistent)
    a = {}; a.A = WP(O_S1); a.aZ = 4194304; a.lda = 256;
    a.Bw = WP(O_WOUTP) + (size_t)d0*65536; a.bZ = 65536; a.ldb = 256;
    a.bias = outpB + d0*256; a.biasZ = 256;
    a.C = WP(O_OUTS) + (size_t)d0*4194304; a.cZ = 4194304; a.ldc = 256; a.colOff = 0; a.K = 256;
    gemm_bt<0,0><<<dim3(128,2,nd), 256, 0, stream>>>(a);
  }

  // 20. final inverse-permute average + residual
  finalk<<<4096, 256, 0, stream>>>(curr, WP(O_OUTS), (float*)d_out);

  #undef WP
  #undef FP
}

// Round 16
// 696.645 us; speedup vs baseline: 1.0540x; 1.0540x over previous
//
#include <hip/hip_runtime.h>
#include <hip/hip_bf16.h>
#include <cstdint>
#include <cstddef>

typedef unsigned short u16;
typedef unsigned int u32;
typedef __attribute__((ext_vector_type(8))) __bf16 bfx8;
typedef __attribute__((ext_vector_type(4))) float f32x4;

static __device__ __forceinline__ float bitf(u32 v){ float f; __builtin_memcpy(&f,&v,4); return f; }
static __device__ __forceinline__ float bf2f(u16 v){ return bitf(((u32)v)<<16); }
static __device__ __forceinline__ u16 f2bf(float f){ __bf16 b=(__bf16)f; u16 r; __builtin_memcpy(&r,&b,2); return r; }
static __device__ __forceinline__ u32 pk2(float a,float b){ return (u32)f2bf(a) | ((u32)f2bf(b)<<16); }
static __device__ __forceinline__ void unpk8(uint4 r, float* o){
  o[0]=bitf(r.x<<16); o[1]=bitf(r.x&0xffff0000u);
  o[2]=bitf(r.y<<16); o[3]=bitf(r.y&0xffff0000u);
  o[4]=bitf(r.z<<16); o[5]=bitf(r.z&0xffff0000u);
  o[6]=bitf(r.w<<16); o[7]=bitf(r.w&0xffff0000u);
}
static __device__ __forceinline__ void unpk4(uint2 r, float* o){
  o[0]=bitf(r.x<<16); o[1]=bitf(r.x&0xffff0000u);
  o[2]=bitf(r.y<<16); o[3]=bitf(r.y&0xffff0000u);
}
static __device__ __forceinline__ void async16(void* lds, const void* g){
  __builtin_amdgcn_global_load_lds((const __attribute__((address_space(1))) u32*)g,
                                   (__attribute__((address_space(3))) u32*)lds, 16, 0, 0);
}

// ---------------- GEMM: C[M][N] = A[M][K] @ B[N][K]^T (+ epilogue) -----------
// EPI: 0=+bias, 2=BN+ReLU, 3=+bias+add, 4=raw fp32, 5=*rowsc+bias+add, 6=raw bf16
// AMODE 2: conv3 dy-grouped split-K (z = dy+1, K=1536, dx from k0>>9)
struct GemmArgs {
  const u16* A; long aZ; int lda;
  const u16* Bw; long bZ; int ldb;
  const float* bias; int biasZ;
  const float* scale; const float* shift;
  const u16* add; long addZ;
  const float* rowsc; long rowscZ;
  u16* C; long cZ; int ldc; int colOff;
  int K;
  const u16* pad;
  int dirBase;
};

template<int AMODE, int EPI>
__global__ __launch_bounds__(256)
void gemm_bt(GemmArgs g)
{
  __shared__ u16 smA[128*64];
  __shared__ u16 smB[128*64];
  const int tid = threadIdx.x;
  const int l = tid & 63;
  const int wv = tid >> 6;
  const int wr = wv >> 1, wc = wv & 1;
  const int z = blockIdx.z;
  const int r0 = blockIdx.x * 128;
  const int n0 = blockIdx.y * 128;

  const u16* Abase = g.A + (size_t)z * g.aZ;
  const u16* Bbase = g.Bw + (size_t)z * g.bZ;
  const int ldb = g.ldb ? g.ldb : g.K;

  f32x4 acc[4][4];
  #pragma unroll
  for (int i=0;i<4;i++)
    #pragma unroll
    for (int j=0;j<4;j++) acc[i][j] = (f32x4){0.f,0.f,0.f,0.f};

  const int nkt = g.K >> 6;
  #pragma unroll 1
  for (int kt=0; kt<nkt; ++kt) {
    const int k0 = kt << 6;
    #pragma unroll
    for (int it=0; it<4; ++it) {
      const int s = it*256 + tid;
      const int row = s >> 3, ch = s & 7;
      const u16* ga;
      if (AMODE == 0) {
        ga = Abase + (size_t)(r0+row) * g.lda + k0 + ch*8;
      } else if (AMODE == 1) {
        int rr = r0 + row; int li = rr & 4095; int bb = rr >> 12;
        int dir = g.dirBase + z;
        int l2 = (dir & 2) ? (4095 - li) : li;
        int sl = (dir & 1) ? (((l2 & 63) << 6) | (l2 >> 6)) : l2;
        ga = Abase + (size_t)((bb << 12) | sl) * g.lda + k0 + ch*8;
      } else if (AMODE == 2) {
        int rr = r0 + row; int bb = rr >> 12; int li = rr & 4095;
        int yy = li >> 6, xx = li & 63;
        int dy = z - 1, dx = (k0 >> 9) - 1, kin = k0 & 511;
        ga = g.pad + (((size_t)(bb*66 + yy+dy+1))*66 + (xx+dx+1))*512 + kin + ch*8;
      } else {
        int rr = r0 + row; int bb = rr >> 12; int li = rr & 4095;
        int yy = li >> 6, xx = li & 63;
        ga = g.pad + (((size_t)(bb*66 + yy+1))*66 + (xx+1))*512 + k0 + ch*8;
      }
      async16(&smA[(size_t)(it*256 + (tid & ~63))*8], ga);
      const u16* gb = Bbase + (size_t)(n0+row) * ldb + k0 + ch*8;
      async16(&smB[(size_t)(it*256 + (tid & ~63))*8], gb);
    }
    __syncthreads();
    #pragma unroll
    for (int kk=0; kk<2; ++kk) {
      bfx8 av[4], bv[4];
      #pragma unroll
      for (int mi=0; mi<4; ++mi) {
        int ra = wr*64 + mi*16 + (l & 15);
        av[mi] = *(const bfx8*)&smA[ra*64 + kk*32 + (l>>4)*8];
      }
      #pragma unroll
      for (int ni=0; ni<4; ++ni) {
        int rb = wc*64 + ni*16 + (l & 15);
        bv[ni] = *(const bfx8*)&smB[rb*64 + kk*32 + (l>>4)*8];
      }
      #pragma unroll
      for (int mi=0; mi<4; ++mi)
        #pragma unroll
        for (int ni=0; ni<4; ++ni)
          acc[mi][ni] = __builtin_amdgcn_mfma_f32_16x16x32_bf16(av[mi], bv[ni], acc[mi][ni], 0, 0, 0);
    }
    __syncthreads();
  }

  const float* bias_d = (EPI == 0 || EPI == 3 || EPI == 5) ? g.bias + (size_t)z * g.biasZ : nullptr;
  const u16* add_d = (EPI == 3 || EPI == 5) ? g.add + (size_t)z * g.addZ : nullptr;
  const float* rowsc_d = (EPI == 5) ? g.rowsc + (size_t)z * g.rowscZ : nullptr;
  u16* Cd = g.C + (size_t)z * g.cZ;
  float* Cf = (float*)g.C + (size_t)z * g.cZ;
  #pragma unroll
  for (int mi=0; mi<4; ++mi) {
    #pragma unroll
    for (int ni=0; ni<4; ++ni) {
      f32x4 v = acc[mi][ni];
      const int gr = r0 + wr*64 + mi*16 + ((l >> 4) << 2);
      const int gc = n0 + wc*64 + ni*16 + (l & 15);
      #pragma unroll
      for (int q=0; q<4; ++q) {
        const int r = gr + q;
        float x = v[q];
        if (EPI == 2) {
          x = fmaxf(fmaf(x, g.scale[gc], g.shift[gc]), 0.f);
          Cd[(size_t)r * g.ldc + g.colOff + gc] = f2bf(x);
        } else if (EPI == 3) {
          x += bias_d[gc] + bf2f(add_d[(size_t)r * g.ldc + gc]);
          Cd[(size_t)r * g.ldc + g.colOff + gc] = f2bf(x);
        } else if (EPI == 5) {
          x = x * rowsc_d[r] + bias_d[gc] + bf2f(add_d[(size_t)r * g.ldc + gc]);
          Cd[(size_t)r * g.ldc + g.colOff + gc] = f2bf(x);
        } else if (EPI == 4) {
          Cf[(size_t)r * g.ldc + g.colOff + gc] = x;
        } else if (EPI == 6) {
          Cd[(size_t)r * g.ldc + g.colOff + gc] = f2bf(x);
        } else {
          x += bias_d[gc];
          Cd[(size_t)r * g.ldc + g.colOff + gc] = f2bf(x);
        }
      }
    }
  }
}

// ---------------- small utility kernels --------------------------------------
__global__ void castk(const float* __restrict__ s, u16* __restrict__ d, int n)
{
  int i = (blockIdx.x*256 + threadIdx.x)*4;
  if (i < n){
    float4 v = *(const float4*)(s+i);
    ushort4 o; o.x=f2bf(v.x); o.y=f2bf(v.y); o.z=f2bf(v.z); o.w=f2bf(v.w);
    *(ushort4*)(d+i) = o;
  }
}

// cast m_out W with norm gain folded in
__global__ void castg(const float* __restrict__ s, const float* __restrict__ gw,
                      u16* __restrict__ d)
{
  int i = (blockIdx.x*256 + threadIdx.x)*4;
  int dd = i >> 17, k = i & 511;
  float4 v = *(const float4*)(s+i);
  float4 g4 = *(const float4*)(gw + dd*512 + k);
  ushort4 o; o.x=f2bf(v.x*g4.x); o.y=f2bf(v.y*g4.y); o.z=f2bf(v.z*g4.z); o.w=f2bf(v.w*g4.w);
  *(ushort4*)(d+i) = o;
}

__global__ void c3rep(const float* __restrict__ w, u16* __restrict__ o)
{
  int id = blockIdx.x*256 + threadIdx.x;
  int oc = id / 4608, rem = id % 4608;
  int tap = rem >> 9, ic = rem & 511;
  o[id] = f2bf(w[((size_t)oc*512 + ic)*9 + tap]);
}

__global__ void bnssk(const float* g3,const float* b3,const float* m3,const float* v3,
                      const float* g1,const float* b1,const float* m1,const float* v1,
                      float* out)
{
  int t = threadIdx.x; int i = t & 127;
  if (t < 128){ float sc = g3[i]*rsqrtf(v3[i]+1e-5f); out[i]=sc; out[128+i]=b3[i]-m3[i]*sc; }
  else        { float sc = g1[i]*rsqrtf(v1[i]+1e-5f); out[256+i]=sc; out[384+i]=b1[i]-m1[i]*sc; }
}

// reduce 3 bf16 partials -> BN+ReLU -> bf16 into zin cols 0..127
__global__ __launch_bounds__(256)
void c3red(const u16* __restrict__ P, const float* __restrict__ bnss, u16* __restrict__ zin)
{
  const int id = blockIdx.x*256 + threadIdx.x;
  const size_t base = (size_t)id * 8;
  const int r = (int)(base >> 7), c = (int)(base & 127);
  float s[8] = {0,0,0,0,0,0,0,0};
  #pragma unroll
  for (int z=0; z<3; ++z){
    uint4 raw = *(const uint4*)(P + (size_t)z*2097152 + base);
    float v[8]; unpk8(raw, v);
    #pragma unroll
    for (int j=0;j<8;j++) s[j] += v[j];
  }
  uint4 o;
  float r8[8];
  #pragma unroll
  for (int j=0;j<8;j++)
    r8[j] = fmaxf(fmaf(s[j], bnss[c+j], bnss[128+c+j]), 0.f);
  o.x = pk2(r8[0],r8[1]); o.y = pk2(r8[2],r8[3]);
  o.z = pk2(r8[4],r8[5]); o.w = pk2(r8[6],r8[7]);
  *(uint4*)(zin + (size_t)r*256 + c) = o;
}

__global__ __launch_bounds__(256)
void padk(const float* __restrict__ curr, const float* __restrict__ prev, u16* __restrict__ pad)
{
  const int id = blockIdx.x*256 + threadIdx.x;
  const int c8 = id & 63;
  int t = id >> 6;
  const int xx = t % 66; t /= 66;
  const int yy = t % 66; const int b = t / 66;
  const int c0 = c8*8;
  uint4 o;
  if (yy==0 || yy==65 || xx==0 || xx==65){ o.x=0;o.y=0;o.z=0;o.w=0; }
  else {
    const int l = (yy-1)*64 + (xx-1);
    const float* s = (c0 < 256) ? curr + ((size_t)b*4096 + l)*256 + c0
                                : prev + ((size_t)b*4096 + l)*256 + (c0-256);
    float4 a = *(const float4*)s, bb = *(const float4*)(s+4);
    o.x = pk2(a.x,a.y); o.y = pk2(a.z,a.w); o.z = pk2(bb.x,bb.y); o.w = pk2(bb.z,bb.w);
  }
  *(uint4*)(pad + (((size_t)b*66 + yy)*66 + xx)*512 + c0) = o;
}

__global__ __launch_bounds__(256)
void ln256(const u16* __restrict__ in, long inZ, u16* __restrict__ out, long outZ,
           const float* __restrict__ gw, const float* __restrict__ bw, int pz)
{
  const int z = blockIdx.z;
  const int row = blockIdx.x*4 + (threadIdx.x>>6);
  const int l = threadIdx.x & 63;
  const u16* ip = in + (size_t)z*inZ + (size_t)row*256 + l*4;
  ushort4 rr = *(const ushort4*)ip;
  float v0=bf2f(rr.x), v1=bf2f(rr.y), v2=bf2f(rr.z), v3=bf2f(rr.w);
  float s = v0+v1+v2+v3;
  float ss = v0*v0+v1*v1+v2*v2+v3*v3;
  #pragma unroll
  for(int m=1;m<64;m<<=1){ s += __shfl_xor(s,m); ss += __shfl_xor(ss,m); }
  float mu = s*(1.f/256.f);
  float var = ss*(1.f/256.f) - mu*mu;
  float rs = rsqrtf(var + 1e-5f);
  const float* g = gw + (size_t)z*pz; const float* b = bw + (size_t)z*pz;
  int c = l*4;
  u16* op = out + (size_t)z*outZ + (size_t)row*256 + c;
  ushort4 o; o.x=f2bf((v0-mu)*rs*g[c]+b[c]); o.y=f2bf((v1-mu)*rs*g[c+1]+b[c+1]);
  o.z=f2bf((v2-mu)*rs*g[c+2]+b[c+2]); o.w=f2bf((v3-mu)*rs*g[c+3]+b[c+3]);
  *(ushort4*)op = o;
}

// sum 8 head partial SS -> inverse RMS per row
__global__ __launch_bounds__(256)
void rsumk(const float* __restrict__ RS8, float* __restrict__ RS)
{
  const int z = blockIdx.z;
  const int row = blockIdx.x*256 + threadIdx.x;
  const float* p = RS8 + ((size_t)z*16384 + row)*8;
  float4 a = *(const float4*)p, b = *(const float4*)(p+4);
  float s = a.x+a.y+a.z+a.w+b.x+b.y+b.z+b.w;
  RS[(size_t)z*16384 + row] = rsqrtf(s*(1.f/512.f) + 1e-5f);
}

// fp32 dt head: dt = softplus(xln.W_dt + b + dt_bias)
__global__ __launch_bounds__(256)
void dtk(const u16* __restrict__ xln, const float* __restrict__ minW,
         const float* __restrict__ minB, const float* __restrict__ dtb,
         float* __restrict__ DT)
{
  __shared__ float sx[32*257];
  const int z = blockIdx.z;
  const int r0 = blockIdx.x * 32;
  const int tid = threadIdx.x;
  {
    const int rr = tid >> 3, cc = (tid & 7) * 32;
    const u16* src = xln + ((size_t)z*16384 + r0 + rr)*256 + cc;
    #pragma unroll
    for (int q=0;q<4;q++){
      uint4 raw = *(const uint4*)(src + q*8);
      float v[8]; unpk8(raw, v);
      #pragma unroll
      for (int j=0;j<8;j++) sx[rr*257 + cc + q*8 + j] = v[j];
    }
  }
  __syncthreads();
  const int ri = tid >> 3, hv = tid & 7;
  const float* wrow = minW + ((size_t)z*1288 + 1280 + hv)*256;
  float acc = 0.f;
  #pragma unroll 4
  for (int k=0; k<256; k+=4){
    float4 wq = *(const float4*)(wrow + k);
    acc += sx[ri*257+k]*wq.x + sx[ri*257+k+1]*wq.y + sx[ri*257+k+2]*wq.z + sx[ri*257+k+3]*wq.w;
  }
  acc += minB[(size_t)z*1288 + 1280 + hv] + dtb[z*8 + hv];
  float dt = (acc > 20.f) ? acc : log1pf(expf(acc));
  DT[((size_t)z*16384 + r0 + ri)*8 + hv] = dt;
}

// chunk-local cumulative log-decay
__global__ __launch_bounds__(256)
void cak(const float* __restrict__ DT, float* __restrict__ CA,
         const float* __restrict__ alog, int dirBase)
{
  const int z = blockIdx.z;
  const int gidx = blockIdx.x*4 + (threadIdx.x>>6);
  const int lane = threadIdx.x & 63;
  const int c = gidx & 63, bh = gidx >> 6;
  const int b = bh >> 3, hh = bh & 7;
  const size_t row = (size_t)z*16384 + (size_t)b*4096 + c*64 + lane;
  float x = DT[row*8 + hh];
  #pragma unroll
  for (int m=1;m<64;m<<=1){ float o = __shfl_up(x, m); if (lane >= m) x += o; }
  float eA = expf(alog[(dirBase+z)*8 + hh]);
  CA[row*8 + hh] = -eA * x;
}

// fused: conv1d(4)+SiLU on B/C columns + C-half -> BCC + B-transpose -> BT
//        + head-shared raw scores S -> SR.   grid (256,1,nd) per (b,c)
__global__ __launch_bounds__(256)
void bck(const u16* __restrict__ xbcr, u16* __restrict__ bcc, u16* __restrict__ bt,
         u16* __restrict__ SR, const float* __restrict__ cw, const float* __restrict__ cb)
{
  __shared__ u16 BCs[64*264];   // [s][B:0..127, C:128..255]
  __shared__ u16 Tb[128*72];    // [n][s] transposed B
  __shared__ float cwS[4][256];
  __shared__ float cbS[256];
  const int bx = blockIdx.x, z = blockIdx.z;
  const int c = bx & 63, b = bx >> 6;
  const int tid = threadIdx.x, l = tid & 63, w = tid >> 6;
  const u16* xb = xbcr + (size_t)z*16777216 + (size_t)b*4096*768;
  const float* cwp = cw + (size_t)z*3072;
  const float* cbp = cb + (size_t)z*768;
  {
    float4 w4 = *(const float4*)(cwp + (512 + tid)*4);
    cwS[0][tid]=w4.x; cwS[1][tid]=w4.y; cwS[2][tid]=w4.z; cwS[3][tid]=w4.w;
    cbS[tid] = cbp[512 + tid];
  }
  __syncthreads();
  #pragma unroll
  for (int u=0; u<8; ++u){
    int idx = u*256 + tid;
    int s = idx >> 5, c8 = idx & 31;
    int li = c*64 + s;
    int col = 512 + c8*8;
    float acc[8];
    #pragma unroll
    for (int j=0;j<8;j++) acc[j] = cbS[c8*8+j];
    #pragma unroll
    for (int tap=0; tap<4; ++tap){
      int lt = li - 3 + tap;
      if (lt >= 0){
        uint4 raw = *(const uint4*)(xb + (size_t)lt*768 + col);
        float v[8]; unpk8(raw, v);
        #pragma unroll
        for (int j=0;j<8;j++) acc[j] = fmaf(v[j], cwS[tap][c8*8+j], acc[j]);
      }
    }
    u16 o8[8];
    #pragma unroll
    for (int j=0;j<8;j++) o8[j] = f2bf(acc[j] / (1.f + __expf(-acc[j])));
    *(uint4*)&BCs[s*264 + c8*8] = *(const uint4*)o8;
    if (c8 >= 16){
      *(uint4*)(bcc + ((size_t)z*16384 + (size_t)b*4096 + li)*256 + c8*8) = *(const uint4*)o8;
    } else {
      #pragma unroll
      for (int j=0;j<8;j++) Tb[(c8*8+j)*72 + s] = o8[j];
    }
  }
  __syncthreads();
  // S = C@B^T (16 MFMA)
  bfx8 av[4];
  #pragma unroll
  for (int kk=0; kk<4; ++kk)
    av[kk] = *(const bfx8*)&BCs[(w*16 + (l&15))*264 + 128 + kk*32 + (l>>4)*8];
  f32x4 sacc[4];
  #pragma unroll
  for (int i=0;i<4;i++) sacc[i] = (f32x4){0.f,0.f,0.f,0.f};
  #pragma unroll
  for (int kk=0; kk<4; ++kk)
    #pragma unroll
    for (int st=0; st<4; ++st){
      bfx8 bv = *(const bfx8*)&BCs[(st*16 + (l&15))*264 + kk*32 + (l>>4)*8];
      sacc[st] = __builtin_amdgcn_mfma_f32_16x16x32_bf16(av[kk], bv, sacc[st], 0, 0, 0);
    }
  // SR stride per (z,b) is 262144 u16 (64 chunks x 4096)
  u16* Sd = SR + ((size_t)z*4 + b)*262144 + (size_t)c*4096;
  const int t0 = w*16 + ((l>>4)<<2);
  #pragma unroll
  for (int st=0; st<4; ++st){
    int s = st*16 + (l&15);
    u32* cp = (u32*)&Sd[(size_t)s*64 + t0];
    cp[0] = pk2(sacc[st][0], sacc[st][1]);
    cp[1] = pk2(sacc[st][2], sacc[st][3]);
  }
  #pragma unroll
  for (int u=0; u<4; ++u){
    int idx = u*256 + tid;
    int n = idx >> 3, sg = idx & 7;
    uint4 v = *(const uint4*)&Tb[n*72 + sg*8];
    *(uint4*)(bt + (size_t)z*2097152 + (size_t)n*16384 + (size_t)b*4096 + c*64 + sg*8) = v;
  }
}

// conv1d(4)+SiLU on X cols (raw 0..511) + transpose -> XCT[p][g]
__global__ __launch_bounds__(256)
void convx(const u16* __restrict__ xbcr, u16* __restrict__ xct,
           const float* __restrict__ cw, const float* __restrict__ cb)
{
  __shared__ u16 T[128*72];
  __shared__ float cwX[4][128];
  __shared__ float cbX[128];
  const int bx = blockIdx.x, z = blockIdx.z;
  const int pq = bx & 3, c = (bx>>2) & 63, b = bx >> 8;
  const int tid = threadIdx.x;
  const u16* xb = xbcr + (size_t)z*16777216 + (size_t)b*4096*768;
  if (tid < 128){
    float4 w4 = *(const float4*)(cw + (size_t)z*3072 + (pq*128+tid)*4);
    cwX[0][tid]=w4.x; cwX[1][tid]=w4.y; cwX[2][tid]=w4.z; cwX[3][tid]=w4.w;
    cbX[tid] = cb[z*768 + pq*128 + tid];
  }
  __syncthreads();
  #pragma unroll
  for (int u=0; u<4; ++u){
    int idx = u*256 + tid;
    int s = idx >> 4, seg = idx & 15;
    int li = c*64 + s;
    int col = pq*128 + seg*8;
    float acc[8];
    #pragma unroll
    for (int j=0;j<8;j++) acc[j] = cbX[seg*8+j];
    #pragma unroll
    for (int tap=0; tap<4; ++tap){
      int lt = li - 3 + tap;
      if (lt >= 0){
        uint4 raw = *(const uint4*)(xb + (size_t)lt*768 + col);
        float v[8]; unpk8(raw, v);
        #pragma unroll
        for (int j=0;j<8;j++) acc[j] = fmaf(v[j], cwX[tap][seg*8+j], acc[j]);
      }
    }
    #pragma unroll
    for (int j=0;j<8;j++)
      T[(seg*8+j)*72 + s] = f2bf(acc[j] / (1.f + __expf(-acc[j])));
  }
  __syncthreads();
  #pragma unroll
  for (int u=0; u<4; ++u){
    int idx = u*256 + tid;
    int pl = idx >> 3, sg = idx & 7;
    uint4 v = *(const uint4*)&T[pl*72 + sg*8];
    *(uint4*)(xct + (size_t)z*8388608 + (size_t)(pq*128+pl)*16384 + b*4096 + c*64 + sg*8) = v;
  }
}

// per-chunk outer products, heads fused, p-quarter per block; grid (1024,1,nd)
__global__ __launch_bounds__(256)
void csk(const u16* __restrict__ xct, const u16* __restrict__ bt,
         const float* __restrict__ DT, const float* __restrict__ CA,
         u16* __restrict__ CS)
{
  __shared__ u16 Xw[128*72];
  __shared__ u16 Bt[128*72];
  __shared__ float wS[64*2];
  const int bx = blockIdx.x, z = blockIdx.z;
  const int pq = bx & 3, c = (bx>>2) & 63, b = bx >> 8;
  const int tid = threadIdx.x, l = tid & 63, w = tid >> 6;
  const size_t rowb = (size_t)z*16384 + (size_t)b*4096;
  const int p0 = pq*128;
  if (tid < 128){
    int s = tid & 63, hi = tid >> 6;
    int hh = pq*2 + hi;
    float ca63 = CA[(rowb + c*64 + 63)*8 + hh];
    float cav  = CA[(rowb + c*64 + s)*8 + hh];
    float dtv  = DT[(rowb + c*64 + s)*8 + hh];
    wS[s*2+hi] = __expf(ca63 - cav) * dtv;
  }
  __syncthreads();
  #pragma unroll
  for (int u=0; u<4; ++u){
    int idx = u*256 + tid;
    int pl = idx >> 3, sg = idx & 7;
    int hi = pl >> 6;
    uint4 raw = *(const uint4*)(xct + (size_t)z*8388608 + (size_t)(p0+pl)*16384 + b*4096 + c*64 + sg*8);
    float v[8]; unpk8(raw, v);
    uint4 o;
    o.x = pk2(v[0]*wS[(sg*8+0)*2+hi], v[1]*wS[(sg*8+1)*2+hi]);
    o.y = pk2(v[2]*wS[(sg*8+2)*2+hi], v[3]*wS[(sg*8+3)*2+hi]);
    o.z = pk2(v[4]*wS[(sg*8+4)*2+hi], v[5]*wS[(sg*8+5)*2+hi]);
    o.w = pk2(v[6]*wS[(sg*8+6)*2+hi], v[7]*wS[(sg*8+7)*2+hi]);
    *(uint4*)&Xw[pl*72 + sg*8] = o;
  }
  #pragma unroll
  for (int u=0; u<4; ++u){
    int idx = u*256 + tid;
    int n = idx >> 3, sg = idx & 7;
    *(uint4*)&Bt[n*72 + sg*8] =
      *(const uint4*)(bt + (size_t)z*2097152 + (size_t)n*16384 + b*4096 + c*64 + sg*8);
  }
  __syncthreads();
  f32x4 acc[8][2];
  #pragma unroll
  for (int i=0;i<8;i++)
    #pragma unroll
    for (int j=0;j<2;j++) acc[i][j] = (f32x4){0.f,0.f,0.f,0.f};
  #pragma unroll
  for (int kk=0; kk<2; ++kk){
    bfx8 bvp[2];
    #pragma unroll
    for (int ni=0; ni<2; ++ni)
      bvp[ni] = *(const bfx8*)&Xw[(w*32 + ni*16 + (l&15))*72 + kk*32 + (l>>4)*8];
    #pragma unroll
    for (int mi=0; mi<8; ++mi){
      bfx8 av = *(const bfx8*)&Bt[(mi*16 + (l&15))*72 + kk*32 + (l>>4)*8];
      #pragma unroll
      for (int ni=0; ni<2; ++ni)
        acc[mi][ni] = __builtin_amdgcn_mfma_f32_16x16x32_bf16(av, bvp[ni], acc[mi][ni], 0, 0, 0);
    }
  }
  #pragma unroll
  for (int mi=0; mi<8; ++mi){
    #pragma unroll
    for (int ni=0; ni<2; ++ni){
      int gp = p0 + w*32 + ni*16 + (l&15);
      int bhx = b*8 + (gp>>6); int pin = gp & 63;
      int n0 = mi*16 + ((l>>4)<<2);
      u32* cp = (u32*)&CS[(size_t)z*16777216 + (size_t)bhx*524288 + (size_t)c*8192 + (size_t)pin*128 + n0];
      cp[0] = pk2(acc[mi][ni][0], acc[mi][ni][1]);
      cp[1] = pk2(acc[mi][ni][2], acc[mi][ni][3]);
    }
  }
}

// sequential 64-step combine IN PLACE (H aliases CS); 2x n-split
__global__ __launch_bounds__(256)
void combk(const u16* __restrict__ CS, const float* __restrict__ CA,
           u16* __restrict__ H)
{
  __shared__ float aL[64];
  const int bx = blockIdx.x;
  const int z = blockIdx.z;
  const int nh = bx & 1, pg = (bx >> 1) & 3, bh = bx >> 3;
  const int b = bh >> 3, hh = bh & 7;
  const int tid = threadIdx.x;
  const int p = pg*16 + (tid >> 4), n = nh*64 + (tid & 15)*4;
  const size_t rowb = (size_t)z*16384 + (size_t)b*4096;
  if (tid < 64) aL[tid] = __expf(CA[(rowb + tid*64 + 63)*8 + hh]);
  __syncthreads();
  const u16* Cs = CS + (size_t)z*16777216 + (size_t)bh*524288 + (size_t)p*128 + n;
  u16* Hd = H + (size_t)z*16777216 + (size_t)bh*524288 + (size_t)p*128 + n;
  float h[4];
  #pragma unroll
  for (int j=0;j<4;j++) h[j]=0.f;
  uint2 pf = *(const uint2*)Cs;
  #pragma unroll 1
  for (int c=0; c<64; ++c){
    uint2 cur = pf;
    if (c < 63) pf = *(const uint2*)(Cs + (size_t)(c+1)*8192);
    uint2 o;
    o.x = pk2(h[0],h[1]); o.y = pk2(h[2],h[3]);
    *(uint2*)(Hd + (size_t)c*8192) = o;
    float v[4]; unpk4(cur, v);
    const float a = aL[c];
    #pragma unroll
    for (int j=0;j<4;j++) h[j] = fmaf(h[j], a, v[j]);
  }
}

// per-chunk output: Y = (S_decayed @ X + diag(exp(ca)) * (C @ H[c]) + Dh*x) * silu(z)
// scores loaded direct to regs; LDS 36.4KB -> 4 blocks/CU
__global__ __launch_bounds__(256)
void yk2(const u16* __restrict__ bcc, const u16* __restrict__ xct,
         const u16* __restrict__ SR,
         const float* __restrict__ DT, const float* __restrict__ CA,
         const u16* __restrict__ H, const float* __restrict__ Dp,
         u16* __restrict__ Y, float* __restrict__ RS8)
{
  __shared__ u16 Hs[64*136];
  __shared__ u16 Xt[64*72];
  __shared__ u16 Sm[64*72];     // decayed scores; reused as Z/Y tile late
  __shared__ float caL[64], dtL[64];
  const int bx = blockIdx.x, z = blockIdx.z;
  const int c = bx & 63, bh = bx >> 6;
  const int b = bh >> 3, hh = bh & 7;
  const int tid = threadIdx.x, l = tid & 63, w = tid >> 6;
  const size_t rowb = (size_t)z*16384 + (size_t)b*4096;
  const u16* bcp = bcc + (rowb + c*64)*256;
  const u16* Hd = H + (size_t)z*16777216 + (size_t)bh*524288 + (size_t)c*8192;
  const u16* xcp = xct + (size_t)z*8388608 + (size_t)(hh*64)*16384 + b*4096 + c*64;
  const u16* Sd = SR + ((size_t)z*4 + b)*262144 + (size_t)c*4096;
  const float Dh = Dp[z*8 + hh];
  const int t0 = w*16 + ((l>>4)<<2);

  uint2 sv[4];
  #pragma unroll
  for (int st=0; st<4; ++st)
    sv[st] = *(const uint2*)(Sd + (size_t)(st*16 + (l&15))*64 + t0);
  bfx8 av[4];
  #pragma unroll
  for (int kk=0; kk<4; ++kk)
    av[kk] = *(const bfx8*)(bcp + (size_t)(w*16 + (l&15))*256 + 128 + kk*32 + (l>>4)*8);

  if (tid < 64){
    caL[tid] = CA[(rowb + c*64 + tid)*8 + hh];
    dtL[tid] = DT[(rowb + c*64 + tid)*8 + hh];
  }
  #pragma unroll
  for (int u=0; u<4; ++u){
    int idx = u*256 + tid; int p = idx >> 4, sg = idx & 15;
    *(uint4*)&Hs[p*136 + sg*8] = *(const uint4*)(Hd + (size_t)p*128 + sg*8);
  }
  #pragma unroll
  for (int u=0; u<2; ++u){
    int idx = u*256 + tid; int p = idx >> 3, sg = idx & 7;
    *(uint4*)&Xt[p*72 + sg*8] = *(const uint4*)(xcp + (size_t)p*16384 + sg*8);
  }
  __syncthreads();

  f32x4 acc2[4];
  #pragma unroll
  for (int i=0;i<4;i++) acc2[i] = (f32x4){0.f,0.f,0.f,0.f};
  #pragma unroll
  for (int kk=0; kk<4; ++kk)
    #pragma unroll
    for (int st=0; st<4; ++st){
      bfx8 hv = *(const bfx8*)&Hs[(st*16 + (l&15))*136 + kk*32 + (l>>4)*8];
      acc2[st] = __builtin_amdgcn_mfma_f32_16x16x32_bf16(av[kk], hv, acc2[st], 0, 0, 0);
    }
  #pragma unroll
  for (int st=0; st<4; ++st){
    int s = st*16 + (l&15);
    #pragma unroll
    for (int q=0;q<4;q++){
      int t = t0 + q;
      u32 wv2 = (q < 2) ? sv[st].x : sv[st].y;
      u16 sraw = (q & 1) ? (u16)(wv2 >> 16) : (u16)(wv2 & 0xffff);
      float m = (s <= t) ? __expf(caL[t]-caL[s]) * dtL[s] : 0.f;
      Sm[t*72 + s] = f2bf(bf2f(sraw) * m);
    }
  }
  #pragma unroll
  for (int pt=0; pt<4; ++pt)
    #pragma unroll
    for (int q=0;q<4;q++){
      int t = t0 + q;
      acc2[pt][q] *= __expf(caL[t]);
    }
  __syncthreads();          // Sm ready
  #pragma unroll
  for (int kk=0; kk<2; ++kk){
    bfx8 svx = *(const bfx8*)&Sm[(w*16 + (l&15))*72 + kk*32 + (l>>4)*8];
    #pragma unroll
    for (int pt=0; pt<4; ++pt){
      bfx8 bv = *(const bfx8*)&Xt[(pt*16 + (l&15))*72 + kk*32 + (l>>4)*8];
      acc2[pt] = __builtin_amdgcn_mfma_f32_16x16x32_bf16(svx, bv, acc2[pt], 0, 0, 0);
    }
  }
  __syncthreads();          // Sm reads done; reuse as Zs
  u16* Zs = Sm;
  u16* Yrow = Y + (rowb + c*64)*512 + hh*64;
  #pragma unroll
  for (int u=0; u<2; ++u){
    int idx = u*256 + tid; int t = idx >> 3, sg = idx & 7;
    *(uint4*)&Zs[t*72 + sg*8] = *(const uint4*)(Yrow + (size_t)t*512 + sg*8);
  }
  __syncthreads();          // Zs ready
  float ssq[4] = {0.f,0.f,0.f,0.f};
  #pragma unroll
  for (int pt=0; pt<4; ++pt){
    #pragma unroll
    for (int q=0;q<4;q++){
      int t = t0 + q;
      int p = pt*16 + (l&15);
      float xv = bf2f(Xt[p*72 + t]);
      float zf = bf2f(Zs[t*72 + p]);
      float yv = (acc2[pt][q] + Dh*xv) * (zf/(1.f+__expf(-zf)));
      ssq[q] += yv*yv;
      Zs[t*72 + p] = f2bf(yv);
    }
  }
  #pragma unroll
  for (int q=0;q<4;q++){
    float s = ssq[q];
    s += __shfl_xor(s, 1); s += __shfl_xor(s, 2);
    s += __shfl_xor(s, 4); s += __shfl_xor(s, 8);
    if ((l & 15) == 0){
      int t = t0 + q;
      RS8[(rowb + c*64 + t)*8 + hh] = s;
    }
  }
  __syncthreads();
  #pragma unroll
  for (int u=0; u<2; ++u){
    int idx = u*256 + tid; int t = idx >> 3, sg = idx & 7;
    *(uint4*)(Yrow + (size_t)t*512 + sg*8) = *(const uint4*)&Zs[t*72 + sg*8];
  }
}

__global__ __launch_bounds__(256)
void finalk(const float* __restrict__ curr, const u16* __restrict__ outs, float* __restrict__ o)
{
  const int row = blockIdx.x*4 + (threadIdx.x>>6);
  const int c4 = (threadIdx.x & 63)*4;
  const int b = row >> 12, li = row & 4095;
  const int T = ((li & 63) << 6) | (li >> 6);
  const size_t rb = (size_t)b*4096;
  const ushort4 a0 = *(const ushort4*)(outs + (size_t)0*4194304 + ((rb+li)*256 + c4));
  const ushort4 a1 = *(const ushort4*)(outs + (size_t)1*4194304 + ((rb+T)*256 + c4));
  const ushort4 a2 = *(const ushort4*)(outs + (size_t)2*4194304 + ((rb+4095-li)*256 + c4));
  const ushort4 a3 = *(const ushort4*)(outs + (size_t)3*4194304 + ((rb+4095-T)*256 + c4));
  float4 cv = *(const float4*)(curr + (size_t)row*256 + c4);
  float4 r;
  r.x = cv.x + 0.25f*(bf2f(a0.x)+bf2f(a1.x)+bf2f(a2.x)+bf2f(a3.x));
  r.y = cv.y + 0.25f*(bf2f(a0.y)+bf2f(a1.y)+bf2f(a2.y)+bf2f(a3.y));
  r.z = cv.z + 0.25f*(bf2f(a0.z)+bf2f(a1.z)+bf2f(a2.z)+bf2f(a3.z));
  r.w = cv.w + 0.25f*(bf2f(a0.w)+bf2f(a1.w)+bf2f(a2.w)+bf2f(a3.w));
  *(float4*)(o + (size_t)row*256 + c4) = r;
}

// ---------------------------------------------------------------------------
extern "C" void kernel_launch(void* const* d_in, const int* in_sizes, int n_in,
                              void* d_out, int out_size, void* d_ws, size_t ws_size,
                              hipStream_t stream)
{
  (void)in_sizes; (void)n_in; (void)out_size;
  const float* curr   = (const float*)d_in[0];
  const float* prev   = (const float*)d_in[1];
  const float* conv3w = (const float*)d_in[2];
  const float* bn3g=(const float*)d_in[3], *bn3b=(const float*)d_in[4], *bn3m=(const float*)d_in[5], *bn3v=(const float*)d_in[6];
  const float* conv1w = (const float*)d_in[7];
  const float* bn1g=(const float*)d_in[8], *bn1b=(const float*)d_in[9], *bn1m=(const float*)d_in[10], *bn1v=(const float*)d_in[11];
  const float* fuseW=(const float*)d_in[12], *fuseB=(const float*)d_in[13];
  const float* lng=(const float*)d_in[14], *lnb=(const float*)d_in[15];
  const float* inpW=(const float*)d_in[16], *inpB=(const float*)d_in[17];
  const float* mlng=(const float*)d_in[18], *mlnb=(const float*)d_in[19];
  const float* minW=(const float*)d_in[20], *minB=(const float*)d_in[21];
  const float* cw=(const float*)d_in[22], *cb=(const float*)d_in[23];
  const float* alog=(const float*)d_in[24], *Dp=(const float*)d_in[25], *dtb=(const float*)d_in[26];
  const float* mng=(const float*)d_in[27];
  const float* moutW=(const float*)d_in[28], *moutB=(const float*)d_in[29];
  const float* outpW=(const float*)d_in[30], *outpB=(const float*)d_in[31];

  // ---- persistent layout ----
  char* ws = (char*)d_ws;
  size_t off = 0;
  auto alloc = [&](size_t bytes){ size_t o = off; off = (off + bytes + 1023) & ~(size_t)1023; return o; };
  const size_t O_WFUSE = alloc((size_t)256*256*2);
  const size_t O_WINP  = alloc((size_t)4*256*256*2);
  const size_t O_WMIN  = alloc((size_t)4*1288*256*2);
  const size_t O_WMOUT = alloc((size_t)4*256*512*2);
  const size_t O_WOUTP = alloc((size_t)4*256*256*2);
  const size_t O_WC3   = alloc((size_t)128*4608*2);
  const size_t O_WC1   = alloc((size_t)128*512*2);
  const size_t O_BNSS  = alloc(512*4);
  const size_t O_ZF    = alloc((size_t)16384*256*2);
  const size_t O_OUTS  = alloc((size_t)4*16384*256*2);
  const size_t O_P     = off;

  // per-dir sizes (bytes)
  const size_t S0d  = (size_t)16384*256*2;
  const size_t XLNd = (size_t)16384*256*2;
  const size_t Yd   = (size_t)16384*512*2;
  const size_t XCTd = (size_t)512*16384*2;
  const size_t BTd  = (size_t)128*16384*2;
  const size_t DTd  = (size_t)16384*8*4;
  const size_t CAd  = (size_t)16384*8*4;
  const size_t SRd  = (size_t)4*64*4096*2;
  const size_t RSd  = (size_t)16384*4;
  const size_t RS8d = (size_t)16384*8*4;
  const size_t XHd  = (size_t)16777216*2;
  const size_t perdir = S0d + XLNd + Yd + XCTd + BTd + DTd + CAd + SRd + RSd + RS8d + XHd;

  const size_t PADsz = (size_t)4*66*66*512*2;
  const size_t CPsz  = (size_t)3*16384*128*2;   // 3 bf16 partials (dy-grouped)
  const size_t PREsz = PADsz + CPsz + (size_t)16384*256*2*2 + 4096;

  int nd = 0;
  for (int cand = 4; cand >= 1; cand >>= 1) {
    size_t need = (size_t)cand*perdir; if (need < PREsz) need = PREsz;
    if (O_P + need <= ws_size) { nd = cand; break; }
  }
  if (nd == 0) return;

  #define WP(o) ((u16*)(ws + (o)))
  #define FP(o) ((float*)(ws + (o)))

  const size_t O_PAD = O_P;
  const size_t O_CP  = O_PAD + PADsz;
  const size_t O_ZIN = O_CP + CPsz;
  const size_t O_ZFT = O_ZIN + (size_t)16384*256*2;

  // 1. BN scale/shift + weight conversions
  bnssk<<<1, 256, 0, stream>>>(bn3g,bn3b,bn3m,bn3v, bn1g,bn1b,bn1m,bn1v, FP(O_BNSS));
  castk<<<64, 256, 0, stream>>>(fuseW, WP(O_WFUSE), 65536);
  castk<<<256, 256, 0, stream>>>(inpW, WP(O_WINP), 262144);
  castk<<<1288, 256, 0, stream>>>(minW, WP(O_WMIN), 1318912);
  castg<<<512, 256, 0, stream>>>(moutW, mng, WP(O_WMOUT));
  castk<<<256, 256, 0, stream>>>(outpW, WP(O_WOUTP), 262144);
  castk<<<64, 256, 0, stream>>>(conv1w, WP(O_WC1), 65536);
  c3rep<<<2304, 256, 0, stream>>>(conv3w, WP(O_WC3));
  // 2. padded concat input (bf16)
  padk<<<4356, 256, 0, stream>>>(curr, prev, WP(O_PAD));

  GemmArgs a;
  // 3. conv3 dy-grouped split-K (3 passes, K=1536) -> bf16 partials -> reduce+BN+ReLU
  a = {}; a.A = WP(O_PAD); a.pad = WP(O_PAD);
  a.Bw = WP(O_WC3); a.bZ = 1536; a.ldb = 4608;
  a.C = WP(O_CP); a.cZ = 2097152; a.ldc = 128; a.colOff = 0; a.K = 1536;
  gemm_bt<2,6><<<dim3(128,1,3), 256, 0, stream>>>(a);
  c3red<<<1024, 256, 0, stream>>>(WP(O_CP), FP(O_BNSS), WP(O_ZIN));
  // 4. conv1 -> zin[:,128:256]
  a = {}; a.A = WP(O_PAD); a.pad = WP(O_PAD); a.Bw = WP(O_WC1); a.bZ = 0; a.ldb = 512;
  a.scale = FP(O_BNSS)+256; a.shift = FP(O_BNSS)+384;
  a.C = WP(O_ZIN); a.cZ = 0; a.ldc = 256; a.colOff = 128; a.K = 512;
  gemm_bt<3,2><<<dim3(128,1,1), 256, 0, stream>>>(a);
  // 5. fuse GEMM -> zft
  a = {}; a.A = WP(O_ZIN); a.aZ = 0; a.lda = 256; a.Bw = WP(O_WFUSE); a.bZ = 0; a.ldb = 256;
  a.bias = fuseB; a.biasZ = 0; a.C = WP(O_ZFT); a.cZ = 0; a.ldc = 256; a.colOff = 0; a.K = 256;
  gemm_bt<0,0><<<dim3(128,2,1), 256, 0, stream>>>(a);
  // 6. LN -> zf (persistent)
  ln256<<<dim3(4096,1,1), 256, 0, stream>>>(WP(O_ZFT), 0, WP(O_ZF), 0, lng, lnb, 0);

  // ---- phases over directions ----
  for (int d0 = 0; d0 < 4; d0 += nd) {
    size_t o = O_P;
    const size_t O_S0  = o; o += (size_t)nd*S0d;
    const size_t O_XLN = o; o += (size_t)nd*XLNd;
    const size_t O_Y   = o; o += (size_t)nd*Yd;
    const size_t O_XCT = o; o += (size_t)nd*XCTd;
    const size_t O_BT  = o; o += (size_t)nd*BTd;
    const size_t O_DT  = o; o += (size_t)nd*DTd;
    const size_t O_CA  = o; o += (size_t)nd*CAd;
    const size_t O_SR  = o; o += (size_t)nd*SRd;
    const size_t O_RS  = o; o += (size_t)nd*RSd;
    const size_t O_RS8 = o; o += (size_t)nd*RS8d;
    const size_t O_XH  = o;
    const size_t O_BCC = O_XLN;
    const size_t O_S1  = O_XLN;

    // 7. inp GEMM (permuted rows per dir) -> s0
    a = {}; a.A = WP(O_ZF); a.aZ = 0; a.lda = 256;
    a.Bw = WP(O_WINP) + (size_t)d0*65536; a.bZ = 65536; a.ldb = 256;
    a.bias = inpB + d0*256; a.biasZ = 256;
    a.C = WP(O_S0); a.cZ = 4194304; a.ldc = 256; a.colOff = 0; a.K = 256; a.dirBase = d0;
    gemm_bt<1,0><<<dim3(128,2,nd), 256, 0, stream>>>(a);
    // 8. per-dir LN(s0) -> xln
    ln256<<<dim3(4096,1,nd), 256, 0, stream>>>(WP(O_S0), 4194304, WP(O_XLN), 4194304,
                                               mlng + d0*256, mlnb + d0*256, 256);
    // 9. dt, chunk log-decay
    dtk<<<dim3(512,1,nd), 256, 0, stream>>>(WP(O_XLN), minW + (size_t)d0*329728,
                                            minB + d0*1288, dtb + d0*8, FP(O_DT));
    cak<<<dim3(512,1,nd), 256, 0, stream>>>(FP(O_DT), FP(O_CA), alog, d0);
    // 10. z-gate GEMM -> Y
    a = {}; a.A = WP(O_XLN); a.aZ = 4194304; a.lda = 256;
    a.Bw = WP(O_WMIN) + (size_t)d0*329728; a.bZ = 329728; a.ldb = 256;
    a.bias = minB + d0*1288; a.biasZ = 1288;
    a.C = WP(O_Y); a.cZ = 8388608; a.ldc = 512; a.colOff = 0; a.K = 256;
    gemm_bt<0,0><<<dim3(128,4,nd), 256, 0, stream>>>(a);
    // 11. xBC GEMM -> raw xbc   [last reader of XLN]
    a = {}; a.A = WP(O_XLN); a.aZ = 4194304; a.lda = 256;
    a.Bw = WP(O_WMIN) + (size_t)d0*329728 + (size_t)512*256; a.bZ = 329728; a.ldb = 256;
    a.bias = minB + d0*1288 + 512; a.biasZ = 1288;
    a.C = WP(O_XH); a.cZ = 16777216; a.ldc = 768; a.colOff = 0; a.K = 256;
    gemm_bt<0,0><<<dim3(128,6,nd), 256, 0, stream>>>(a);
    // 12. conv1d+SiLU+transpose X -> XCT
    convx<<<dim3(1024,1,nd), 256, 0, stream>>>(WP(O_XH), WP(O_XCT), cw + d0*3072, cb + d0*768);
    // 13. fused conv B/C + BCC(C-half) + BT + head-shared scores SR
    bck<<<dim3(256,1,nd), 256, 0, stream>>>(WP(O_XH), WP(O_BCC), WP(O_BT), WP(O_SR),
                                            cw + d0*3072, cb + d0*768);
    // 14. per-chunk outer products -> CS (overlays raw xbc; after 12&13)
    csk<<<dim3(1024,1,nd), 256, 0, stream>>>(WP(O_XCT), WP(O_BT), FP(O_DT), FP(O_CA), WP(O_XH));
    // 15. 64-step combine in place -> H
    combk<<<dim3(256,1,nd), 256, 0, stream>>>(WP(O_XH), FP(O_CA), WP(O_XH));
    // 16. per-chunk outputs -> Y in place, + per-(row,head) SS
    yk2<<<dim3(2048,1,nd), 256, 0, stream>>>(WP(O_BCC), WP(O_XCT), WP(O_SR),
                                             FP(O_DT), FP(O_CA), WP(O_XH), Dp + d0*8,
                                             WP(O_Y), FP(O_RS8));
    // 17. inverse RMS per row
    rsumk<<<dim3(64,1,nd), 256, 0, stream>>>(FP(O_RS8), FP(O_RS));
    // 18. m_out GEMM (norm fused) + s0 residual -> s1
    a = {}; a.A = WP(O_Y); a.aZ = 8388608; a.lda = 512;
    a.Bw = WP(O_WMOUT) + (size_t)d0*131072; a.bZ = 131072; a.ldb = 512;
    a.bias = moutB + d0*256; a.biasZ = 256;
    a.add = WP(O_S0); a.addZ = 4194304;
    a.rowsc = FP(O_RS); a.rowscZ = 16384;
    a.C = WP(O_S1); a.cZ = 4194304; a.ldc = 256; a.colOff = 0; a.K = 512;
    gemm_bt<0,5><<<dim3(128,2,nd), 256, 0, stream>>>(a);
    // 19. outp GEMM -> outs (persistent)
    a = {}; a.A = WP(O_S1); a.aZ = 4194304; a.lda = 256;
    a.Bw = WP(O_WOUTP) + (size_t)d0*65536; a.bZ = 65536; a.ldb = 256;
    a.bias = outpB + d0*256; a.biasZ = 256;
    a.C = WP(O_OUTS) + (size_t)d0*4194304; a.cZ = 4194304; a.ldc = 256; a.colOff = 0; a.K = 256;
    gemm_bt<0,0><<<dim3(128,2,nd), 256, 0, stream>>>(a);
  }

  // 20. final inverse-permute average + residual
  finalk<<<4096, 256, 0, stream>>>(curr, WP(O_OUTS), (float*)d_out);

  #undef WP
  #undef FP
}